// Round 4
// baseline (256.143 us; speedup 1.0000x reference)
//
#include <hip/hip_runtime.h>
#include <hip/hip_bf16.h>
#include <math.h>

typedef unsigned short u16;
typedef unsigned int   u32;
typedef __attribute__((ext_vector_type(8))) short bf16x8;
typedef __attribute__((ext_vector_type(4))) float f32x4;
typedef __attribute__((ext_vector_type(4))) unsigned short u16x4;
typedef __attribute__((ext_vector_type(4))) unsigned int   u32x4;

#define T_SEQ 2048
#define BATCH 2
#define NHEAD 16
#define KVHEADS 4
#define HD 128
#define DM 2048
#define QKV_N 3072
#define MROWS 4096

__device__ __forceinline__ float bf2f(u16 u) {
    union { u32 i; float f; } v; v.i = ((u32)u) << 16; return v.f;
}
__device__ __forceinline__ u16 f2bf(float f) {
    u32 x = __float_as_uint(f);
    u32 r = (x + 0x7fffu + ((x >> 16) & 1u)) >> 16;
    return (u16)r;
}

// async global->LDS, 16B per lane; dest = wave-uniform base + lane*16
__device__ __forceinline__ void gl16(const void* g, void* lds) {
    __builtin_amdgcn_global_load_lds(
        (const __attribute__((address_space(1))) void*)g,
        (__attribute__((address_space(3))) void*)lds, 16, 0, 0);
}

// ---------------------------------------------------------------------------
// fp32 -> bf16 elementwise convert
// ---------------------------------------------------------------------------
__global__ void cvt_f32_bf16(const float* __restrict__ in, u16* __restrict__ out, int nq)
{
    int i = blockIdx.x * blockDim.x + threadIdx.x;
    const int stride = gridDim.x * blockDim.x;
    for (; i < nq; i += stride) {
        f32x4 v = ((const f32x4*)in)[i];
        u16x4 o = { f2bf(v[0]), f2bf(v[1]), f2bf(v[2]), f2bf(v[3]) };
        ((u16x4*)out)[i] = o;
    }
}

// ---------------------------------------------------------------------------
// GEMM: C[M,N] = A[M,K] @ B[N,K]^T + bias  (bf16 tiles, fp32 acc)
// 128x128 tile, BK=64, 256 threads. Staging via global_load_lds width=16:
// linear LDS dest, pre-swizzled global source (src slot = slot^(row&7)),
// swizzled ds_read_b128 (byte ^= (row&7)<<4) -> involution consistent.
// ---------------------------------------------------------------------------
template <int EPI>
__global__ __launch_bounds__(256, 4)
void gemm_bt(const u16* __restrict__ A, const u16* __restrict__ Bw,
             const float* __restrict__ bias, u16* __restrict__ C,
             float* __restrict__ Cf, u16* __restrict__ Vt, int M, int N, int K)
{
    __shared__ __align__(16) u16 As[128 * 64];
    __shared__ __align__(16) u16 Bs[128 * 64];

    const int tid = threadIdx.x;
    const int l = tid & 63;
    const int w = tid >> 6;
    const int wr = w >> 1, wc = w & 1;
    const int bm = blockIdx.x, bn = blockIdx.y;

    // gload_lds source mapping: shot j covers rows w*8+j*32 .. +7 (128B rows)
    const int lrow = l >> 3;                 // row within shot
    const int lsl  = (l & 7) ^ lrow;         // pre-swizzled source slot
    const size_t aBase = (size_t)(bm * 128 + w * 8 + lrow) * K + lsl * 8;
    const size_t bBase = (size_t)(bn * 128 + w * 8 + lrow) * K + lsl * 8;

    // fragment read offsets (bytes), kk toggled via ^(kk<<6)
    const int sw = (l & 7) << 4;
    int offA[4], offB[4];
#pragma unroll
    for (int mf = 0; mf < 4; ++mf)
        offA[mf] = (wr * 64 + mf * 16 + (l & 15)) * 128 + (((l >> 4) * 16) ^ sw);
#pragma unroll
    for (int nf = 0; nf < 4; ++nf)
        offB[nf] = (wc * 64 + nf * 16 + (l & 15)) * 128 + (((l >> 4) * 16) ^ sw);

    f32x4 acc[4][4];
#pragma unroll
    for (int i = 0; i < 4; ++i)
#pragma unroll
        for (int j = 0; j < 4; ++j)
            acc[i][j] = (f32x4){0.f, 0.f, 0.f, 0.f};

    const int nK = K >> 6;
    for (int kt = 0; kt < nK; ++kt) {
        __syncthreads();   // prior tile's reads complete (no-op at kt=0)
#pragma unroll
        for (int j = 0; j < 4; ++j) {
            gl16(A  + aBase + (size_t)j * 32 * K + kt * 64,
                 (char*)As + (w * 8 + j * 32) * 128);
            gl16(Bw + bBase + (size_t)j * 32 * K + kt * 64,
                 (char*)Bs + (w * 8 + j * 32) * 128);
        }
        __syncthreads();   // drains vmcnt -> tiles staged
#pragma unroll
        for (int kk = 0; kk < 2; ++kk) {
            bf16x8 af[4], bfr[4];
#pragma unroll
            for (int mf = 0; mf < 4; ++mf)
                af[mf] = *(const bf16x8*)((const char*)As + (offA[mf] ^ (kk << 6)));
#pragma unroll
            for (int nf = 0; nf < 4; ++nf)
                bfr[nf] = *(const bf16x8*)((const char*)Bs + (offB[nf] ^ (kk << 6)));
            __builtin_amdgcn_s_setprio(1);
#pragma unroll
            for (int mf = 0; mf < 4; ++mf)
#pragma unroll
                for (int nf = 0; nf < 4; ++nf)
                    acc[mf][nf] = __builtin_amdgcn_mfma_f32_16x16x32_bf16(
                        af[mf], bfr[nf], acc[mf][nf], 0, 0, 0);
            __builtin_amdgcn_s_setprio(0);
        }
    }

    // epilogue: C/D layout col=l&15, row=(l>>4)*4+i
    const int row0 = bm * 128 + wr * 64 + ((l >> 4) << 2);
    const int col0 = bn * 128 + wc * 64 + (l & 15);
#pragma unroll
    for (int mf = 0; mf < 4; ++mf) {
#pragma unroll
        for (int nf = 0; nf < 4; ++nf) {
            const int row = row0 + mf * 16;
            const int col = col0 + nf * 16;
            const float bv = bias[col];
            float v0 = acc[mf][nf][0] + bv;
            float v1 = acc[mf][nf][1] + bv;
            float v2 = acc[mf][nf][2] + bv;
            float v3 = acc[mf][nf][3] + bv;
            if (EPI == 0) {
                if (col < 2560) {  // Q + K region -> row-major qkv (bf16)
                    C[(size_t)(row + 0) * QKV_N + col] = f2bf(v0);
                    C[(size_t)(row + 1) * QKV_N + col] = f2bf(v1);
                    C[(size_t)(row + 2) * QKV_N + col] = f2bf(v2);
                    C[(size_t)(row + 3) * QKV_N + col] = f2bf(v3);
                } else {           // V region -> transposed Vt[b][kvh][d][t] (bf16)
                    const int dd = col - 2560;
                    const int kv = dd >> 7;
                    const int d = dd & 127;
                    const int bidx = row >> 11;
                    const int tt = row & 2047;
                    u16x4 pv = {f2bf(v0), f2bf(v1), f2bf(v2), f2bf(v3)};
                    *(u16x4*)(Vt + ((size_t)((bidx * KVHEADS + kv) * HD + d)) * T_SEQ + tt) = pv;
                }
            } else {               // final output: fp32
                Cf[(size_t)(row + 0) * DM + col] = v0;
                Cf[(size_t)(row + 1) * DM + col] = v1;
                Cf[(size_t)(row + 2) * DM + col] = v2;
                Cf[(size_t)(row + 3) * DM + col] = v3;
            }
        }
    }
}

// ---------------------------------------------------------------------------
// Flash attention v3: 512 threads (8 waves), KVBLK=128, s-split.
// Waves 0-3 = s-half 0, waves 4-7 = s-half 1; each wave owns 16 q-rows of the
// shared 64-row q-tile. Pairing (px, 31-px) -> every block exactly 17 chunks.
// K/V staged via global_load_lds (linear dest, pre-swizzled source).
// Group merge of (m,l,O) through LDS at each q-tile end.
// ---------------------------------------------------------------------------
__global__ __launch_bounds__(512, 4)
void attn_fwd(const u16* __restrict__ qkv, const u16* __restrict__ Vt,
              u16* __restrict__ AO)
{
    __shared__ __align__(16) u16 Ks[128 * 128];   // [s][d]  32KB
    __shared__ __align__(16) u16 Vs[128 * 128];   // [d][s]  32KB
    __shared__ __align__(16) u16 Ps[8 * 16 * 64]; // per-wave P, 16KB

    const int tid = threadIdx.x;
    const int l = tid & 63;
    const int w = tid >> 6;          // 0..7
    const int wq = w & 3;            // q-row group
    const int g  = w >> 2;           // s-half
    const int b = blockIdx.y >> 4;
    const int h = blockIdx.y & 15;
    const int kvh = h >> 2;
    const int px = blockIdx.x;       // 0..15

    // staging: shot j covers rows w*16+j*4 .. +3 (256B rows, 16 slots)
    const int srow = l >> 4;                       // 0..3
    const int so0 = ((l & 15) ^ srow) * 8;         // src elem offset, j even
    const int so1 = ((l & 15) ^ (srow + 4)) * 8;   // j odd
    const size_t gK0 = (size_t)(b * T_SEQ) * QKV_N + 2048 + kvh * HD;
    const size_t gV0 = (size_t)((b * KVHEADS + kvh) * HD) * T_SEQ;

    const int sw = (l & 7) << 4;

    // ALiBi: slope = 2^(-(h+1)/2)
    const float slope = exp2f(-0.5f * (float)(h + 1));
    const float scale = 0.08838834764831845f;      // 1/sqrt(128)

    const int n0 = (px >> 1) + 1;
    int qt = px;
    int q0 = qt << 6;

    // Q fragments: row = wq*16 + (l&15), k-slice = kk*32 + (l>>4)*8
    const size_t qcol_off = (size_t)h * HD + ((l >> 4) << 3);
    bf16x8 qreg[4];
#pragma unroll
    for (int kk = 0; kk < 4; ++kk)
        qreg[kk] = *(const bf16x8*)(qkv +
            (size_t)(b * T_SEQ + q0 + wq * 16 + (l & 15)) * QKV_N + qcol_off + kk * 32);

    float m_run[4], l_run[4];
    f32x4 o[8];
#pragma unroll
    for (int i = 0; i < 4; ++i) { m_run[i] = -1e30f; l_run[i] = 0.f; }
#pragma unroll
    for (int nf = 0; nf < 8; ++nf) o[nf] = (f32x4){0.f, 0.f, 0.f, 0.f};

    // merge-and-write epilogue for current q-tile (uses Ks as exchange buffer)
    auto FLUSH = [&]() {
        __syncthreads();                       // all compute on this q-tile done
        if (g == 1) {
            float* OX = (float*)Ks + wq * 2048 + l * 32;
#pragma unroll
            for (int nf = 0; nf < 8; ++nf)
                *(f32x4*)(OX + ((nf ^ (l & 7)) << 2)) = o[nf];
            if ((l & 15) == 0) {
                float* Pm = (float*)Ps;
#pragma unroll
                for (int i = 0; i < 4; ++i) {
                    Pm[wq * 16 + ((l >> 4) << 2) + i] = m_run[i];
                    Pm[64 + wq * 16 + ((l >> 4) << 2) + i] = l_run[i];
                }
            }
        }
        __syncthreads();
        if (g == 0) {
            const float* Pm = (const float*)Ps;
            float cA[4], cB[4], rinv[4];
#pragma unroll
            for (int i = 0; i < 4; ++i) {
                const float mb = Pm[wq * 16 + ((l >> 4) << 2) + i];
                const float lb = Pm[64 + wq * 16 + ((l >> 4) << 2) + i];
                const float m = fmaxf(m_run[i], mb);
                cA[i] = __expf(m_run[i] - m);
                cB[i] = __expf(mb - m);
                rinv[i] = 1.f / (l_run[i] * cA[i] + lb * cB[i]);
            }
            const float* OX = (const float*)Ks + wq * 2048 + l * 32;
            const size_t orow = (size_t)(b * T_SEQ + q0 + wq * 16 + ((l >> 4) << 2));
#pragma unroll
            for (int nf = 0; nf < 8; ++nf) {
                f32x4 ob = *(const f32x4*)(OX + ((nf ^ (l & 7)) << 2));
                const int col = h * HD + nf * 16 + (l & 15);
#pragma unroll
                for (int i = 0; i < 4; ++i)
                    AO[(orow + i) * DM + col] =
                        f2bf((o[nf][i] * cA[i] + ob[i] * cB[i]) * rinv[i]);
            }
        }
    };

    for (int it = 0; it < 17; ++it) {
        if (it == n0) {
            FLUSH();
            qt = 31 - px;
            q0 = qt << 6;
#pragma unroll
            for (int kk = 0; kk < 4; ++kk)
                qreg[kk] = *(const bf16x8*)(qkv +
                    (size_t)(b * T_SEQ + q0 + wq * 16 + (l & 15)) * QKV_N + qcol_off + kk * 32);
#pragma unroll
            for (int i = 0; i < 4; ++i) { m_run[i] = -1e30f; l_run[i] = 0.f; }
#pragma unroll
            for (int nf = 0; nf < 8; ++nf) o[nf] = (f32x4){0.f, 0.f, 0.f, 0.f};
        }
        const int jt = (it < n0) ? it : it - n0;
        const int s0 = jt << 7;
        const bool diag = (jt == (qt >> 1));
        const int tb = q0 + wq * 16 + ((l >> 4) << 2);

        __syncthreads();   // prior chunk's reads (or merge reads) complete
#pragma unroll
        for (int j = 0; j < 4; ++j) {
            const int so = (j & 1) ? so1 : so0;
            const int r = w * 16 + j * 4 + srow;
            gl16(qkv + gK0 + (size_t)(s0 + r) * QKV_N + so,
                 (char*)Ks + (w * 16 + j * 4) * 256);
            gl16(Vt + gV0 + (size_t)r * T_SEQ + s0 + so,
                 (char*)Vs + (w * 16 + j * 4) * 256);
        }
        __syncthreads();   // staged (vmcnt drained by barrier)

        // ---- S = Q K^T : wave's 16 rows x its 64 s-cols ----
        f32x4 sc[4];
#pragma unroll
        for (int nf = 0; nf < 4; ++nf) sc[nf] = (f32x4){0.f, 0.f, 0.f, 0.f};
        __builtin_amdgcn_s_setprio(1);
#pragma unroll
        for (int kk = 0; kk < 4; ++kk) {
#pragma unroll
            for (int nf = 0; nf < 4; ++nf) {
                const int offk = (g * 64 + nf * 16 + (l & 15)) * 256 +
                                 ((((l >> 4) * 16) ^ sw) ^ (kk << 6));
                bf16x8 kb = *(const bf16x8*)((const char*)Ks + offk);
                sc[nf] = __builtin_amdgcn_mfma_f32_16x16x32_bf16(qreg[kk], kb, sc[nf], 0, 0, 0);
            }
        }
        __builtin_amdgcn_s_setprio(0);

        // ---- scale + alibi + causal mask (diagonal chunk only) ----
#pragma unroll
        for (int nf = 0; nf < 4; ++nf) {
            const int scol = s0 + g * 64 + nf * 16 + (l & 15);
#pragma unroll
            for (int i = 0; i < 4; ++i) {
                const int trow = tb + i;
                const float xv = sc[nf][i] * scale + slope * (float)(scol - trow);
                sc[nf][i] = (diag && scol > trow) ? -__builtin_inff() : xv;
            }
        }

        // ---- online softmax (rows in 16-lane groups) ----
        float tm[4];
#pragma unroll
        for (int i = 0; i < 4; ++i) {
            float mx = fmaxf(fmaxf(sc[0][i], sc[1][i]), fmaxf(sc[2][i], sc[3][i]));
#pragma unroll
            for (int d = 1; d < 16; d <<= 1) mx = fmaxf(mx, __shfl_xor(mx, d, 64));
            tm[i] = mx;
        }
        float corr[4];
#pragma unroll
        for (int i = 0; i < 4; ++i) {
            const float mn = fmaxf(m_run[i], tm[i]);
            corr[i] = __expf(m_run[i] - mn);
            m_run[i] = mn;
        }
        float ps[4] = {0.f, 0.f, 0.f, 0.f};
#pragma unroll
        for (int nf = 0; nf < 4; ++nf)
#pragma unroll
            for (int i = 0; i < 4; ++i) {
                const float p = __expf(sc[nf][i] - m_run[i]);
                sc[nf][i] = p;
                ps[i] += p;
            }
#pragma unroll
        for (int i = 0; i < 4; ++i) {
#pragma unroll
            for (int d = 1; d < 16; d <<= 1) ps[i] += __shfl_xor(ps[i], d, 64);
            l_run[i] = l_run[i] * corr[i] + ps[i];
        }
#pragma unroll
        for (int nf = 0; nf < 8; ++nf) {
            o[nf][0] *= corr[0]; o[nf][1] *= corr[1];
            o[nf][2] *= corr[2]; o[nf][3] *= corr[3];
        }

        // ---- P -> per-wave LDS (bf16, swizzled) ----
        const int pbase = w * 2048;
#pragma unroll
        for (int nf = 0; nf < 4; ++nf)
#pragma unroll
            for (int i = 0; i < 4; ++i) {
                const int r = ((l >> 4) << 2) + i;
                const int off = pbase + ((r * 128 + nf * 32 + ((l & 15) << 1)) ^ ((r & 7) << 4));
                *(u16*)((char*)Ps + off) = f2bf(sc[nf][i]);
            }

        // ---- O += P @ V (wave's s-half) ----
        const int rp = l & 15;
        __builtin_amdgcn_s_setprio(1);
#pragma unroll
        for (int kk = 0; kk < 2; ++kk) {
            bf16x8 pfr = *(const bf16x8*)((const char*)Ps + pbase +
                          (rp * 128 + ((((l >> 4) * 16) ^ sw) ^ (kk << 6))));
#pragma unroll
            for (int nf = 0; nf < 8; ++nf) {
                const int offv = (nf * 16 + (l & 15)) * 256 + (g << 7) +
                                 ((((l >> 4) * 16) ^ sw) ^ (kk << 6));
                bf16x8 vb = *(const bf16x8*)((const char*)Vs + offv);
                o[nf] = __builtin_amdgcn_mfma_f32_16x16x32_bf16(pfr, vb, o[nf], 0, 0, 0);
            }
        }
        __builtin_amdgcn_s_setprio(0);
    }

    FLUSH();
}

// ---------------------------------------------------------------------------
extern "C" void kernel_launch(void* const* d_in, const int* in_sizes, int n_in,
                              void* d_out, int out_size, void* d_ws, size_t ws_size,
                              hipStream_t stream)
{
    const float* x      = (const float*)d_in[0];
    // d_in[1] = attn_mask (causal, analytic)
    // d_in[2] = alibi_bias (analytic)
    const float* qkv_w  = (const float*)d_in[3];
    const float* qkv_b  = (const float*)d_in[4];
    const float* proj_w = (const float*)d_in[5];
    const float* proj_b = (const float*)d_in[6];
    float* out = (float*)d_out;

    u16* ws  = (u16*)d_ws;
    u16* xb  = ws;                                   // 4096*2048
    u16* AO  = ws;                                   // alias: x dead after gemm0
    u16* qwb = ws + 8388608;                         // 3072*2048
    u16* pwb = qwb + 6291456;                        // 2048*2048
    u16* qkv = pwb + 4194304;                        // 4096*3072
    u16* Vt  = qkv + 12582912;                       // 2*4*128*2048

    cvt_f32_bf16<<<2048, 256, 0, stream>>>(x,      xb,  8388608 / 4);
    cvt_f32_bf16<<<2048, 256, 0, stream>>>(qkv_w,  qwb, 6291456 / 4);
    cvt_f32_bf16<<<1024, 256, 0, stream>>>(proj_w, pwb, 4194304 / 4);

    gemm_bt<0><<<dim3(32, 24), 256, 0, stream>>>(xb, qwb, qkv_b, qkv, nullptr, Vt,
                                                 MROWS, QKV_N, DM);
    attn_fwd<<<dim3(16, 32), 512, 0, stream>>>(qkv, Vt, AO);
    gemm_bt<1><<<dim3(32, 16), 256, 0, stream>>>(AO, pwb, proj_b, nullptr, out, nullptr,
                                                 MROWS, DM, DM);
}

// Round 5
// 232.179 us; speedup vs baseline: 1.1032x; 1.1032x over previous
//
#include <hip/hip_runtime.h>
#include <hip/hip_bf16.h>
#include <math.h>

typedef unsigned short u16;
typedef unsigned int   u32;
typedef __attribute__((ext_vector_type(8))) short bf16x8;
typedef __attribute__((ext_vector_type(4))) float f32x4;
typedef __attribute__((ext_vector_type(4))) unsigned short u16x4;
typedef __attribute__((ext_vector_type(4))) unsigned int   u32x4;

#define T_SEQ 2048
#define BATCH 2
#define NHEAD 16
#define KVHEADS 4
#define HD 128
#define DM 2048
#define QKV_N 3072
#define MROWS 4096

__device__ __forceinline__ float bf2f(u16 u) {
    union { u32 i; float f; } v; v.i = ((u32)u) << 16; return v.f;
}
__device__ __forceinline__ u16 f2bf(float f) {
    u32 x = __float_as_uint(f);
    u32 r = (x + 0x7fffu + ((x >> 16) & 1u)) >> 16;
    return (u16)r;
}

// async global->LDS, 16B per lane; dest = wave-uniform base + lane*16
__device__ __forceinline__ void gl16(const void* g, void* lds) {
    __builtin_amdgcn_global_load_lds(
        (const __attribute__((address_space(1))) void*)g,
        (__attribute__((address_space(3))) void*)lds, 16, 0, 0);
}

// ---------------------------------------------------------------------------
// fp32 -> bf16 elementwise convert
// ---------------------------------------------------------------------------
__global__ void cvt_f32_bf16(const float* __restrict__ in, u16* __restrict__ out, int nq)
{
    int i = blockIdx.x * blockDim.x + threadIdx.x;
    const int stride = gridDim.x * blockDim.x;
    for (; i < nq; i += stride) {
        f32x4 v = ((const f32x4*)in)[i];
        u16x4 o = { f2bf(v[0]), f2bf(v[1]), f2bf(v[2]), f2bf(v[3]) };
        ((u16x4*)out)[i] = o;
    }
}

// ---------------------------------------------------------------------------
// GEMM: C[M,N] = A[M,K] @ B[N,K]^T + bias  (bf16 tiles, fp32 acc)
// 128x128 tile, BK=64, 256 threads. Staging via global_load_lds width=16:
// linear LDS dest, pre-swizzled global source (src slot = slot^(row&7)),
// swizzled ds_read_b128 (byte ^= (row&7)<<4) -> involution consistent.
// launch_bounds (256,3): 168-VGPR cap, matches m97 register profile.
// ---------------------------------------------------------------------------
template <int EPI>
__global__ __launch_bounds__(256, 3)
void gemm_bt(const u16* __restrict__ A, const u16* __restrict__ Bw,
             const float* __restrict__ bias, u16* __restrict__ C,
             float* __restrict__ Cf, u16* __restrict__ Vt, int M, int N, int K)
{
    __shared__ __align__(16) u16 As[128 * 64];
    __shared__ __align__(16) u16 Bs[128 * 64];

    const int tid = threadIdx.x;
    const int l = tid & 63;
    const int w = tid >> 6;
    const int wr = w >> 1, wc = w & 1;
    const int bm = blockIdx.x, bn = blockIdx.y;

    // gload_lds source mapping: shot j covers rows w*8+j*32 .. +7 (128B rows)
    const int lrow = l >> 3;                 // row within shot
    const int lsl  = (l & 7) ^ lrow;         // pre-swizzled source slot
    const size_t aBase = (size_t)(bm * 128 + w * 8 + lrow) * K + lsl * 8;
    const size_t bBase = (size_t)(bn * 128 + w * 8 + lrow) * K + lsl * 8;

    // fragment read offsets (bytes), kk toggled via ^(kk<<6)
    const int sw = (l & 7) << 4;
    int offA[4], offB[4];
#pragma unroll
    for (int mf = 0; mf < 4; ++mf)
        offA[mf] = (wr * 64 + mf * 16 + (l & 15)) * 128 + (((l >> 4) * 16) ^ sw);
#pragma unroll
    for (int nf = 0; nf < 4; ++nf)
        offB[nf] = (wc * 64 + nf * 16 + (l & 15)) * 128 + (((l >> 4) * 16) ^ sw);

    f32x4 acc[4][4];
#pragma unroll
    for (int i = 0; i < 4; ++i)
#pragma unroll
        for (int j = 0; j < 4; ++j)
            acc[i][j] = (f32x4){0.f, 0.f, 0.f, 0.f};

    const int nK = K >> 6;
    for (int kt = 0; kt < nK; ++kt) {
        __syncthreads();   // prior tile's reads complete (no-op at kt=0)
#pragma unroll
        for (int j = 0; j < 4; ++j) {
            gl16(A  + aBase + (size_t)j * 32 * K + kt * 64,
                 (char*)As + (w * 8 + j * 32) * 128);
            gl16(Bw + bBase + (size_t)j * 32 * K + kt * 64,
                 (char*)Bs + (w * 8 + j * 32) * 128);
        }
        __syncthreads();   // drains vmcnt -> tiles staged
#pragma unroll
        for (int kk = 0; kk < 2; ++kk) {
            bf16x8 af[4], bfr[4];
#pragma unroll
            for (int mf = 0; mf < 4; ++mf)
                af[mf] = *(const bf16x8*)((const char*)As + (offA[mf] ^ (kk << 6)));
#pragma unroll
            for (int nf = 0; nf < 4; ++nf)
                bfr[nf] = *(const bf16x8*)((const char*)Bs + (offB[nf] ^ (kk << 6)));
            __builtin_amdgcn_s_setprio(1);
#pragma unroll
            for (int mf = 0; mf < 4; ++mf)
#pragma unroll
                for (int nf = 0; nf < 4; ++nf)
                    acc[mf][nf] = __builtin_amdgcn_mfma_f32_16x16x32_bf16(
                        af[mf], bfr[nf], acc[mf][nf], 0, 0, 0);
            __builtin_amdgcn_s_setprio(0);
        }
    }

    // epilogue: C/D layout col=l&15, row=(l>>4)*4+i
    const int row0 = bm * 128 + wr * 64 + ((l >> 4) << 2);
    const int col0 = bn * 128 + wc * 64 + (l & 15);
#pragma unroll
    for (int mf = 0; mf < 4; ++mf) {
#pragma unroll
        for (int nf = 0; nf < 4; ++nf) {
            const int row = row0 + mf * 16;
            const int col = col0 + nf * 16;
            const float bv = bias[col];
            float v0 = acc[mf][nf][0] + bv;
            float v1 = acc[mf][nf][1] + bv;
            float v2 = acc[mf][nf][2] + bv;
            float v3 = acc[mf][nf][3] + bv;
            if (EPI == 0) {
                if (col < 2560) {  // Q + K region -> row-major qkv (bf16)
                    C[(size_t)(row + 0) * QKV_N + col] = f2bf(v0);
                    C[(size_t)(row + 1) * QKV_N + col] = f2bf(v1);
                    C[(size_t)(row + 2) * QKV_N + col] = f2bf(v2);
                    C[(size_t)(row + 3) * QKV_N + col] = f2bf(v3);
                } else {           // V region -> transposed Vt[b][kvh][d][t] (bf16)
                    const int dd = col - 2560;
                    const int kv = dd >> 7;
                    const int d = dd & 127;
                    const int bidx = row >> 11;
                    const int tt = row & 2047;
                    u16x4 pv = {f2bf(v0), f2bf(v1), f2bf(v2), f2bf(v3)};
                    *(u16x4*)(Vt + ((size_t)((bidx * KVHEADS + kv) * HD + d)) * T_SEQ + tt) = pv;
                }
            } else {               // final output: fp32
                Cf[(size_t)(row + 0) * DM + col] = v0;
                Cf[(size_t)(row + 1) * DM + col] = v1;
                Cf[(size_t)(row + 2) * DM + col] = v2;
                Cf[(size_t)(row + 3) * DM + col] = v3;
            }
        }
    }
}

// ---------------------------------------------------------------------------
// Flash attention v3b: 512 threads (8 waves), KVBLK=128, s-split.
// Waves 0-3 = s-half 0, waves 4-7 = s-half 1; each wave owns 16 q-rows of the
// shared 64-row q-tile. Pairing (px, 31-px) -> every block exactly 17 chunks.
// K/V staged via global_load_lds (linear dest, pre-swizzled source).
// Group merge of (m,l,O) through LDS at each q-tile end.
// launch_bounds (512,2): 128-VGPR cap (r4's (512,4) forced 64 VGPR -> spills;
// LDS=80KB caps residency at 2 blocks/CU regardless).
// ---------------------------------------------------------------------------
__global__ __launch_bounds__(512, 2)
void attn_fwd(const u16* __restrict__ qkv, const u16* __restrict__ Vt,
              u16* __restrict__ AO)
{
    __shared__ __align__(16) u16 Ks[128 * 128];   // [s][d]  32KB
    __shared__ __align__(16) u16 Vs[128 * 128];   // [d][s]  32KB
    __shared__ __align__(16) u16 Ps[8 * 16 * 64]; // per-wave P, 16KB

    const int tid = threadIdx.x;
    const int l = tid & 63;
    const int w = tid >> 6;          // 0..7
    const int wq = w & 3;            // q-row group
    const int g  = w >> 2;           // s-half
    const int b = blockIdx.y >> 4;
    const int h = blockIdx.y & 15;
    const int kvh = h >> 2;
    const int px = blockIdx.x;       // 0..15

    // staging: shot j covers rows w*16+j*4 .. +3 (256B rows, 16 slots)
    const int srow = l >> 4;                       // 0..3
    const int so0 = ((l & 15) ^ srow) * 8;         // src elem offset, j even
    const int so1 = ((l & 15) ^ (srow + 4)) * 8;   // j odd
    const size_t gK0 = (size_t)(b * T_SEQ) * QKV_N + 2048 + kvh * HD;
    const size_t gV0 = (size_t)((b * KVHEADS + kvh) * HD) * T_SEQ;

    const int sw = (l & 7) << 4;

    // ALiBi: slope = 2^(-(h+1)/2)
    const float slope = exp2f(-0.5f * (float)(h + 1));
    const float scale = 0.08838834764831845f;      // 1/sqrt(128)

    const int n0 = (px >> 1) + 1;
    int qt = px;
    int q0 = qt << 6;

    // Q fragments: row = wq*16 + (l&15), k-slice = kk*32 + (l>>4)*8
    const size_t qcol_off = (size_t)h * HD + ((l >> 4) << 3);
    bf16x8 qreg[4];
#pragma unroll
    for (int kk = 0; kk < 4; ++kk)
        qreg[kk] = *(const bf16x8*)(qkv +
            (size_t)(b * T_SEQ + q0 + wq * 16 + (l & 15)) * QKV_N + qcol_off + kk * 32);

    float m_run[4], l_run[4];
    f32x4 o[8];
#pragma unroll
    for (int i = 0; i < 4; ++i) { m_run[i] = -1e30f; l_run[i] = 0.f; }
#pragma unroll
    for (int nf = 0; nf < 8; ++nf) o[nf] = (f32x4){0.f, 0.f, 0.f, 0.f};

    // merge-and-write epilogue for current q-tile (uses Ks as exchange buffer)
    auto FLUSH = [&]() {
        __syncthreads();                       // all compute on this q-tile done
        if (g == 1) {
            float* OX = (float*)Ks + wq * 2048 + l * 32;
#pragma unroll
            for (int nf = 0; nf < 8; ++nf)
                *(f32x4*)(OX + ((nf ^ (l & 7)) << 2)) = o[nf];
            if ((l & 15) == 0) {
                float* Pm = (float*)Ps;
#pragma unroll
                for (int i = 0; i < 4; ++i) {
                    Pm[wq * 16 + ((l >> 4) << 2) + i] = m_run[i];
                    Pm[64 + wq * 16 + ((l >> 4) << 2) + i] = l_run[i];
                }
            }
        }
        __syncthreads();
        if (g == 0) {
            const float* Pm = (const float*)Ps;
            float cA[4], cB[4], rinv[4];
#pragma unroll
            for (int i = 0; i < 4; ++i) {
                const float mb = Pm[wq * 16 + ((l >> 4) << 2) + i];
                const float lb = Pm[64 + wq * 16 + ((l >> 4) << 2) + i];
                const float m = fmaxf(m_run[i], mb);
                cA[i] = __expf(m_run[i] - m);
                cB[i] = __expf(mb - m);
                rinv[i] = 1.f / (l_run[i] * cA[i] + lb * cB[i]);
            }
            const float* OX = (const float*)Ks + wq * 2048 + l * 32;
            const size_t orow = (size_t)(b * T_SEQ + q0 + wq * 16 + ((l >> 4) << 2));
#pragma unroll
            for (int nf = 0; nf < 8; ++nf) {
                f32x4 ob = *(const f32x4*)(OX + ((nf ^ (l & 7)) << 2));
                const int col = h * HD + nf * 16 + (l & 15);
#pragma unroll
                for (int i = 0; i < 4; ++i)
                    AO[(orow + i) * DM + col] =
                        f2bf((o[nf][i] * cA[i] + ob[i] * cB[i]) * rinv[i]);
            }
        }
    };

    for (int it = 0; it < 17; ++it) {
        if (it == n0) {
            FLUSH();
            qt = 31 - px;
            q0 = qt << 6;
#pragma unroll
            for (int kk = 0; kk < 4; ++kk)
                qreg[kk] = *(const bf16x8*)(qkv +
                    (size_t)(b * T_SEQ + q0 + wq * 16 + (l & 15)) * QKV_N + qcol_off + kk * 32);
#pragma unroll
            for (int i = 0; i < 4; ++i) { m_run[i] = -1e30f; l_run[i] = 0.f; }
#pragma unroll
            for (int nf = 0; nf < 8; ++nf) o[nf] = (f32x4){0.f, 0.f, 0.f, 0.f};
        }
        const int jt = (it < n0) ? it : it - n0;
        const int s0 = jt << 7;
        const bool diag = (jt == (qt >> 1));
        const int tb = q0 + wq * 16 + ((l >> 4) << 2);

        __syncthreads();   // prior chunk's reads (or merge reads) complete
#pragma unroll
        for (int j = 0; j < 4; ++j) {
            const int so = (j & 1) ? so1 : so0;
            const int r = w * 16 + j * 4 + srow;
            gl16(qkv + gK0 + (size_t)(s0 + r) * QKV_N + so,
                 (char*)Ks + (w * 16 + j * 4) * 256);
            gl16(Vt + gV0 + (size_t)r * T_SEQ + s0 + so,
                 (char*)Vs + (w * 16 + j * 4) * 256);
        }
        __syncthreads();   // staged (vmcnt drained by barrier)

        // ---- S = Q K^T : wave's 16 rows x its 64 s-cols ----
        f32x4 sc[4];
#pragma unroll
        for (int nf = 0; nf < 4; ++nf) sc[nf] = (f32x4){0.f, 0.f, 0.f, 0.f};
        __builtin_amdgcn_s_setprio(1);
#pragma unroll
        for (int kk = 0; kk < 4; ++kk) {
#pragma unroll
            for (int nf = 0; nf < 4; ++nf) {
                const int offk = (g * 64 + nf * 16 + (l & 15)) * 256 +
                                 ((((l >> 4) * 16) ^ sw) ^ (kk << 6));
                bf16x8 kb = *(const bf16x8*)((const char*)Ks + offk);
                sc[nf] = __builtin_amdgcn_mfma_f32_16x16x32_bf16(qreg[kk], kb, sc[nf], 0, 0, 0);
            }
        }
        __builtin_amdgcn_s_setprio(0);

        // ---- scale + alibi + causal mask (diagonal chunk only) ----
#pragma unroll
        for (int nf = 0; nf < 4; ++nf) {
            const int scol = s0 + g * 64 + nf * 16 + (l & 15);
#pragma unroll
            for (int i = 0; i < 4; ++i) {
                const int trow = tb + i;
                const float xv = sc[nf][i] * scale + slope * (float)(scol - trow);
                sc[nf][i] = (diag && scol > trow) ? -__builtin_inff() : xv;
            }
        }

        // ---- online softmax (rows in 16-lane groups) ----
        float tm[4];
#pragma unroll
        for (int i = 0; i < 4; ++i) {
            float mx = fmaxf(fmaxf(sc[0][i], sc[1][i]), fmaxf(sc[2][i], sc[3][i]));
#pragma unroll
            for (int d = 1; d < 16; d <<= 1) mx = fmaxf(mx, __shfl_xor(mx, d, 64));
            tm[i] = mx;
        }
        float corr[4];
#pragma unroll
        for (int i = 0; i < 4; ++i) {
            const float mn = fmaxf(m_run[i], tm[i]);
            corr[i] = __expf(m_run[i] - mn);
            m_run[i] = mn;
        }
        float ps[4] = {0.f, 0.f, 0.f, 0.f};
#pragma unroll
        for (int nf = 0; nf < 4; ++nf)
#pragma unroll
            for (int i = 0; i < 4; ++i) {
                const float p = __expf(sc[nf][i] - m_run[i]);
                sc[nf][i] = p;
                ps[i] += p;
            }
#pragma unroll
        for (int i = 0; i < 4; ++i) {
#pragma unroll
            for (int d = 1; d < 16; d <<= 1) ps[i] += __shfl_xor(ps[i], d, 64);
            l_run[i] = l_run[i] * corr[i] + ps[i];
        }
#pragma unroll
        for (int nf = 0; nf < 8; ++nf) {
            o[nf][0] *= corr[0]; o[nf][1] *= corr[1];
            o[nf][2] *= corr[2]; o[nf][3] *= corr[3];
        }

        // ---- P -> per-wave LDS (bf16, swizzled) ----
        const int pbase = w * 2048;
#pragma unroll
        for (int nf = 0; nf < 4; ++nf)
#pragma unroll
            for (int i = 0; i < 4; ++i) {
                const int r = ((l >> 4) << 2) + i;
                const int off = pbase + ((r * 128 + nf * 32 + ((l & 15) << 1)) ^ ((r & 7) << 4));
                *(u16*)((char*)Ps + off) = f2bf(sc[nf][i]);
            }

        // ---- O += P @ V (wave's s-half) ----
        const int rp = l & 15;
        __builtin_amdgcn_s_setprio(1);
#pragma unroll
        for (int kk = 0; kk < 2; ++kk) {
            bf16x8 pfr = *(const bf16x8*)((const char*)Ps + pbase +
                          (rp * 128 + ((((l >> 4) * 16) ^ sw) ^ (kk << 6))));
#pragma unroll
            for (int nf = 0; nf < 8; ++nf) {
                const int offv = (nf * 16 + (l & 15)) * 256 + (g << 7) +
                                 ((((l >> 4) * 16) ^ sw) ^ (kk << 6));
                bf16x8 vb = *(const bf16x8*)((const char*)Vs + offv);
                o[nf] = __builtin_amdgcn_mfma_f32_16x16x32_bf16(pfr, vb, o[nf], 0, 0, 0);
            }
        }
        __builtin_amdgcn_s_setprio(0);
    }

    FLUSH();
}

// ---------------------------------------------------------------------------
extern "C" void kernel_launch(void* const* d_in, const int* in_sizes, int n_in,
                              void* d_out, int out_size, void* d_ws, size_t ws_size,
                              hipStream_t stream)
{
    const float* x      = (const float*)d_in[0];
    // d_in[1] = attn_mask (causal, analytic)
    // d_in[2] = alibi_bias (analytic)
    const float* qkv_w  = (const float*)d_in[3];
    const float* qkv_b  = (const float*)d_in[4];
    const float* proj_w = (const float*)d_in[5];
    const float* proj_b = (const float*)d_in[6];
    float* out = (float*)d_out;

    u16* ws  = (u16*)d_ws;
    u16* xb  = ws;                                   // 4096*2048
    u16* AO  = ws;                                   // alias: x dead after gemm0
    u16* qwb = ws + 8388608;                         // 3072*2048
    u16* pwb = qwb + 6291456;                        // 2048*2048
    u16* qkv = pwb + 4194304;                        // 4096*3072
    u16* Vt  = qkv + 12582912;                       // 2*4*128*2048

    cvt_f32_bf16<<<2048, 256, 0, stream>>>(x,      xb,  8388608 / 4);
    cvt_f32_bf16<<<2048, 256, 0, stream>>>(qkv_w,  qwb, 6291456 / 4);
    cvt_f32_bf16<<<1024, 256, 0, stream>>>(proj_w, pwb, 4194304 / 4);

    gemm_bt<0><<<dim3(32, 24), 256, 0, stream>>>(xb, qwb, qkv_b, qkv, nullptr, Vt,
                                                 MROWS, QKV_N, DM);
    attn_fwd<<<dim3(16, 32), 512, 0, stream>>>(qkv, Vt, AO);
    gemm_bt<1><<<dim3(32, 16), 256, 0, stream>>>(AO, pwb, proj_b, nullptr, out, nullptr,
                                                 MROWS, DM, DM);
}

// Round 6
// 207.638 us; speedup vs baseline: 1.2336x; 1.1182x over previous
//
#include <hip/hip_runtime.h>
#include <hip/hip_bf16.h>
#include <math.h>

typedef unsigned short u16;
typedef unsigned int   u32;
typedef __attribute__((ext_vector_type(8))) short bf16x8;
typedef __attribute__((ext_vector_type(4))) float f32x4;
typedef __attribute__((ext_vector_type(4))) unsigned short u16x4;
typedef __attribute__((ext_vector_type(4))) unsigned int   u32x4;

#define T_SEQ 2048
#define BATCH 2
#define NHEAD 16
#define KVHEADS 4
#define HD 128
#define DM 2048
#define QKV_N 3072
#define MROWS 4096

__device__ __forceinline__ float bf2f(u16 u) {
    union { u32 i; float f; } v; v.i = ((u32)u) << 16; return v.f;
}
__device__ __forceinline__ u16 f2bf(float f) {
    u32 x = __float_as_uint(f);
    u32 r = (x + 0x7fffu + ((x >> 16) & 1u)) >> 16;
    return (u16)r;
}

// async global->LDS, 16B per lane; dest = wave-uniform base + lane*16
__device__ __forceinline__ void gl16(const void* g, void* lds) {
    __builtin_amdgcn_global_load_lds(
        (const __attribute__((address_space(1))) void*)g,
        (__attribute__((address_space(3))) void*)lds, 16, 0, 0);
}

// ---------------------------------------------------------------------------
// fp32 -> bf16 elementwise convert
// ---------------------------------------------------------------------------
__global__ void cvt_f32_bf16(const float* __restrict__ in, u16* __restrict__ out, int nq)
{
    int i = blockIdx.x * blockDim.x + threadIdx.x;
    const int stride = gridDim.x * blockDim.x;
    for (; i < nq; i += stride) {
        f32x4 v = ((const f32x4*)in)[i];
        u16x4 o = { f2bf(v[0]), f2bf(v[1]), f2bf(v[2]), f2bf(v[3]) };
        ((u16x4*)out)[i] = o;
    }
}

// ---------------------------------------------------------------------------
// GEMM: C[M,N] = A[M,K] @ B[N,K]^T + bias  (bf16 tiles, fp32 acc)
// 128x128 tile, BK=64, 256 threads. Staging via global_load_lds width=16:
// linear LDS dest, pre-swizzled global source (src slot = slot^(row&7)),
// swizzled ds_read_b128 (byte ^= (row&7)<<4) -> involution consistent.
// launch_bounds (256,3): 170-VGPR cap, matches m97 register profile.
// ---------------------------------------------------------------------------
template <int EPI>
__global__ __launch_bounds__(256, 3)
void gemm_bt(const u16* __restrict__ A, const u16* __restrict__ Bw,
             const float* __restrict__ bias, u16* __restrict__ C,
             float* __restrict__ Cf, u16* __restrict__ Vt, int M, int N, int K)
{
    __shared__ __align__(16) u16 As[128 * 64];
    __shared__ __align__(16) u16 Bs[128 * 64];

    const int tid = threadIdx.x;
    const int l = tid & 63;
    const int w = tid >> 6;
    const int wr = w >> 1, wc = w & 1;
    const int bm = blockIdx.x, bn = blockIdx.y;

    // gload_lds source mapping: shot j covers rows w*8+j*32 .. +7 (128B rows)
    const int lrow = l >> 3;                 // row within shot
    const int lsl  = (l & 7) ^ lrow;         // pre-swizzled source slot
    const size_t aBase = (size_t)(bm * 128 + w * 8 + lrow) * K + lsl * 8;
    const size_t bBase = (size_t)(bn * 128 + w * 8 + lrow) * K + lsl * 8;

    // fragment read offsets (bytes), kk toggled via ^(kk<<6)
    const int sw = (l & 7) << 4;
    int offA[4], offB[4];
#pragma unroll
    for (int mf = 0; mf < 4; ++mf)
        offA[mf] = (wr * 64 + mf * 16 + (l & 15)) * 128 + (((l >> 4) * 16) ^ sw);
#pragma unroll
    for (int nf = 0; nf < 4; ++nf)
        offB[nf] = (wc * 64 + nf * 16 + (l & 15)) * 128 + (((l >> 4) * 16) ^ sw);

    f32x4 acc[4][4];
#pragma unroll
    for (int i = 0; i < 4; ++i)
#pragma unroll
        for (int j = 0; j < 4; ++j)
            acc[i][j] = (f32x4){0.f, 0.f, 0.f, 0.f};

    const int nK = K >> 6;
    for (int kt = 0; kt < nK; ++kt) {
        __syncthreads();   // prior tile's reads complete (no-op at kt=0)
#pragma unroll
        for (int j = 0; j < 4; ++j) {
            gl16(A  + aBase + (size_t)j * 32 * K + kt * 64,
                 (char*)As + (w * 8 + j * 32) * 128);
            gl16(Bw + bBase + (size_t)j * 32 * K + kt * 64,
                 (char*)Bs + (w * 8 + j * 32) * 128);
        }
        __syncthreads();   // drains vmcnt -> tiles staged
#pragma unroll
        for (int kk = 0; kk < 2; ++kk) {
            bf16x8 af[4], bfr[4];
#pragma unroll
            for (int mf = 0; mf < 4; ++mf)
                af[mf] = *(const bf16x8*)((const char*)As + (offA[mf] ^ (kk << 6)));
#pragma unroll
            for (int nf = 0; nf < 4; ++nf)
                bfr[nf] = *(const bf16x8*)((const char*)Bs + (offB[nf] ^ (kk << 6)));
            __builtin_amdgcn_s_setprio(1);
#pragma unroll
            for (int mf = 0; mf < 4; ++mf)
#pragma unroll
                for (int nf = 0; nf < 4; ++nf)
                    acc[mf][nf] = __builtin_amdgcn_mfma_f32_16x16x32_bf16(
                        af[mf], bfr[nf], acc[mf][nf], 0, 0, 0);
            __builtin_amdgcn_s_setprio(0);
        }
    }

    // epilogue: C/D layout col=l&15, row=(l>>4)*4+i
    const int row0 = bm * 128 + wr * 64 + ((l >> 4) << 2);
    const int col0 = bn * 128 + wc * 64 + (l & 15);
#pragma unroll
    for (int mf = 0; mf < 4; ++mf) {
#pragma unroll
        for (int nf = 0; nf < 4; ++nf) {
            const int row = row0 + mf * 16;
            const int col = col0 + nf * 16;
            const float bv = bias[col];
            float v0 = acc[mf][nf][0] + bv;
            float v1 = acc[mf][nf][1] + bv;
            float v2 = acc[mf][nf][2] + bv;
            float v3 = acc[mf][nf][3] + bv;
            if (EPI == 0) {
                if (col < 2560) {  // Q + K region -> row-major qkv (bf16)
                    C[(size_t)(row + 0) * QKV_N + col] = f2bf(v0);
                    C[(size_t)(row + 1) * QKV_N + col] = f2bf(v1);
                    C[(size_t)(row + 2) * QKV_N + col] = f2bf(v2);
                    C[(size_t)(row + 3) * QKV_N + col] = f2bf(v3);
                } else {           // V region -> transposed Vt[b][kvh][d][t] (bf16)
                    const int dd = col - 2560;
                    const int kv = dd >> 7;
                    const int d = dd & 127;
                    const int bidx = row >> 11;
                    const int tt = row & 2047;
                    u16x4 pv = {f2bf(v0), f2bf(v1), f2bf(v2), f2bf(v3)};
                    *(u16x4*)(Vt + ((size_t)((bidx * KVHEADS + kv) * HD + d)) * T_SEQ + tt) = pv;
                }
            } else {               // final output: fp32
                Cf[(size_t)(row + 0) * DM + col] = v0;
                Cf[(size_t)(row + 1) * DM + col] = v1;
                Cf[(size_t)(row + 2) * DM + col] = v2;
                Cf[(size_t)(row + 3) * DM + col] = v3;
            }
        }
    }
}

// ---------------------------------------------------------------------------
// Flash attention v4: round-3 structure + double-buffered K/V LDS.
// Grid (16, B*H), 256 threads (4 waves x 16 q-rows of a 64-row q-tile).
// Block px handles q-tiles {px, 31-px} -> exactly 33 KV-tile iterations.
// Per iter: ONE barrier; issue global->reg prefetch for tile j+1; compute
// tile j from buf[j&1]; ds_write tile j+1 into buf[(j+1)&1] (no conflict
// with readers of buf[j&1]; barrier at next iter top orders buffer reuse).
// Q in registers. All LDS XOR-swizzled (byte ^= (row&7)<<4).
// ---------------------------------------------------------------------------
__global__ __launch_bounds__(256, 2)
void attn_fwd(const u16* __restrict__ qkv, const u16* __restrict__ Vt,
              u16* __restrict__ AO)
{
    __shared__ __align__(16) u16 Ks[2 * 64 * 128];   // 2 x 16KB
    __shared__ __align__(16) u16 Vs[2 * 64 * 128];   // 2 x 16KB
    __shared__ __align__(16) u16 Ps[4 * 16 * 64];    // per-wave P, 8KB

    const int tid = threadIdx.x;
    const int l = tid & 63;
    const int w = tid >> 6;
    const int b = blockIdx.y >> 4;
    const int h = blockIdx.y & 15;
    const int kvh = h >> 2;
    const int px = blockIdx.x;          // 0..15

    const int sw = (l & 7) << 4;
    int offK0[4];
#pragma unroll
    for (int nf = 0; nf < 4; ++nf)
        offK0[nf] = (nf * 16 + (l & 15)) * 256 + (((l >> 4) * 16) ^ sw);

    // staging maps for K and V tiles (byte offsets within one 16KB buffer)
    const int rk = tid >> 4, skk = tid & 15;
    const int loK = rk * 256 + ((skk * 16) ^ ((rk & 7) << 4));
    const size_t gK0 = (size_t)(b * T_SEQ + rk) * QKV_N + 2048 + kvh * HD + skk * 8;
    const int rv = tid >> 3, svv = tid & 7;
    const int loV = rv * 128 + ((svv * 16) ^ ((rv & 7) << 4));
    const size_t gV0 = (size_t)((b * KVHEADS + kvh) * HD + rv) * T_SEQ + svv * 8;

    // ALiBi: slope = 2^(-(h+1)/2); bias = slope*(s-t)
    const float slope = exp2f(-0.5f * (float)(h + 1));
    const float scale = 0.08838834764831845f;      // 1/sqrt(128)

    const int n0 = px + 1;              // tiles for q-tile px
    const int total = 33;               // n0 + (32 - px)

    int qt = px;
    int q0 = qt << 6;

    // Q fragments in registers: frag kk = Q[q0 + w*16 + (l&15)][kk*32 + (l>>4)*8 ..]
    const size_t qrow_off = (size_t)h * HD + ((l >> 4) << 3);
    bf16x8 qreg[4];
#pragma unroll
    for (int kk = 0; kk < 4; ++kk)
        qreg[kk] = *(const bf16x8*)(qkv +
            (size_t)(b * T_SEQ + q0 + w * 16 + (l & 15)) * QKV_N + qrow_off + kk * 32);

    float m_run[4], l_run[4];
    f32x4 o[8];
#pragma unroll
    for (int i = 0; i < 4; ++i) { m_run[i] = -__builtin_inff(); l_run[i] = 0.f; }
#pragma unroll
    for (int nf = 0; nf < 8; ++nf) o[nf] = (f32x4){0.f, 0.f, 0.f, 0.f};

    // prologue: load tile 0 into regs, publish to buffer 0
    u32x4 pk[4], pv[4];
#pragma unroll
    for (int j = 0; j < 4; ++j) {
        pk[j] = *(const u32x4*)(qkv + gK0 + (size_t)(j * 16) * QKV_N);
        pv[j] = *(const u32x4*)(Vt + gV0 + (size_t)j * 32 * T_SEQ);
    }
#pragma unroll
    for (int j = 0; j < 4; ++j) {
        *(u32x4*)((char*)Ks + loK + j * 16 * 256) = pk[j];
        *(u32x4*)((char*)Vs + loV + j * 32 * 128) = pv[j];
    }

    for (int it = 0; it < total; ++it) {
        if (it == n0) {
            // ---- epilogue for q-tile qt, then switch to q-tile 31-px ----
            float rinv[4];
#pragma unroll
            for (int i = 0; i < 4; ++i) rinv[i] = 1.f / l_run[i];
            const size_t orow = (size_t)(b * T_SEQ + q0 + w * 16 + ((l >> 4) << 2));
#pragma unroll
            for (int nf = 0; nf < 8; ++nf) {
                const int col = h * HD + nf * 16 + (l & 15);
#pragma unroll
                for (int i = 0; i < 4; ++i)
                    AO[(orow + i) * DM + col] = f2bf(o[nf][i] * rinv[i]);
            }
            qt = 31 - px;
            q0 = qt << 6;
#pragma unroll
            for (int kk = 0; kk < 4; ++kk)
                qreg[kk] = *(const bf16x8*)(qkv +
                    (size_t)(b * T_SEQ + q0 + w * 16 + (l & 15)) * QKV_N + qrow_off + kk * 32);
#pragma unroll
            for (int i = 0; i < 4; ++i) { m_run[i] = -__builtin_inff(); l_run[i] = 0.f; }
#pragma unroll
            for (int nf = 0; nf < 8; ++nf) o[nf] = (f32x4){0.f, 0.f, 0.f, 0.f};
        }
        const int jt = (it < n0) ? it : it - n0;
        const int s0 = jt << 6;
        const bool diag = (jt == qt);
        const int tb = q0 + w * 16 + ((l >> 4) << 2);
        const int bsel = (it & 1) << 14;        // current K/V buffer (bytes)

        __syncthreads();   // buf[it&1] staged by all; frees buf[(it+1)&1] for overwrite

        // ---- issue global->reg prefetch for tile it+1 (hidden under compute) ----
        const int nit = it + 1;
        if (nit < total) {
            const int ns0 = (nit == n0) ? 0 : (((nit < n0) ? nit : nit - n0) << 6);
#pragma unroll
            for (int j = 0; j < 4; ++j) {
                pk[j] = *(const u32x4*)(qkv + gK0 + (size_t)(ns0 + j * 16) * QKV_N);
                pv[j] = *(const u32x4*)(Vt + gV0 + ns0 + (size_t)j * 32 * T_SEQ);
            }
        }

        // ---- S = Q K^T (wave's 16 rows x 64 cols) ----
        f32x4 sc[4];
#pragma unroll
        for (int nf = 0; nf < 4; ++nf) sc[nf] = (f32x4){0.f, 0.f, 0.f, 0.f};
        __builtin_amdgcn_s_setprio(1);
#pragma unroll
        for (int kk = 0; kk < 4; ++kk) {
#pragma unroll
            for (int nf = 0; nf < 4; ++nf) {
                bf16x8 kb = *(const bf16x8*)((const char*)Ks + bsel + (offK0[nf] ^ (kk << 6)));
                sc[nf] = __builtin_amdgcn_mfma_f32_16x16x32_bf16(qreg[kk], kb, sc[nf], 0, 0, 0);
            }
        }
        __builtin_amdgcn_s_setprio(0);

        // ---- scale + analytic alibi (+ causal mask only on diagonal tile) ----
        float vals[4][4];
#pragma unroll
        for (int nf = 0; nf < 4; ++nf) {
            const int scol = s0 + nf * 16 + (l & 15);
#pragma unroll
            for (int i = 0; i < 4; ++i) {
                const int trow = tb + i;
                const float bias = slope * (float)(scol - trow);
                const float xv = sc[nf][i] * scale + bias;
                vals[nf][i] = (diag && scol > trow) ? -__builtin_inff() : xv;
            }
        }

        // ---- online softmax (rows live in 16-lane groups) ----
        float tm[4];
#pragma unroll
        for (int i = 0; i < 4; ++i) {
            float mx = fmaxf(fmaxf(vals[0][i], vals[1][i]), fmaxf(vals[2][i], vals[3][i]));
#pragma unroll
            for (int d = 1; d < 16; d <<= 1) mx = fmaxf(mx, __shfl_xor(mx, d, 64));
            tm[i] = mx;
        }
        float corr[4];
#pragma unroll
        for (int i = 0; i < 4; ++i) {
            const float mn = fmaxf(m_run[i], tm[i]);
            corr[i] = __expf(m_run[i] - mn);
            m_run[i] = mn;
        }
        float ps[4] = {0.f, 0.f, 0.f, 0.f};
#pragma unroll
        for (int nf = 0; nf < 4; ++nf)
#pragma unroll
            for (int i = 0; i < 4; ++i) {
                const float p = __expf(vals[nf][i] - m_run[i]);
                vals[nf][i] = p;
                ps[i] += p;
            }
#pragma unroll
        for (int i = 0; i < 4; ++i) {
#pragma unroll
            for (int d = 1; d < 16; d <<= 1) ps[i] += __shfl_xor(ps[i], d, 64);
            l_run[i] = l_run[i] * corr[i] + ps[i];
        }
#pragma unroll
        for (int nf = 0; nf < 8; ++nf) {
            o[nf][0] *= corr[0]; o[nf][1] *= corr[1];
            o[nf][2] *= corr[2]; o[nf][3] *= corr[3];
        }

        // ---- P -> per-wave LDS (bf16, swizzled) ----
        const int pbase = w * 2048;
#pragma unroll
        for (int nf = 0; nf < 4; ++nf)
#pragma unroll
            for (int i = 0; i < 4; ++i) {
                const int r = ((l >> 4) << 2) + i;
                const int off = pbase + ((r * 128 + nf * 32 + ((l & 15) << 1)) ^ ((r & 7) << 4));
                *(u16*)((char*)Ps + off) = f2bf(vals[nf][i]);
            }

        // ---- O += P @ V ----
        const int rp = l & 15;
        __builtin_amdgcn_s_setprio(1);
#pragma unroll
        for (int kk = 0; kk < 2; ++kk) {
            bf16x8 pfr = *(const bf16x8*)((const char*)Ps + pbase +
                          (rp * 128 + ((((l >> 4) * 16) ^ sw) ^ (kk << 6))));
#pragma unroll
            for (int nf = 0; nf < 8; ++nf) {
                const int offv = (nf * 16 + (l & 15)) * 128 + ((((l >> 4) * 16) ^ sw) ^ (kk << 6));
                bf16x8 vb = *(const bf16x8*)((const char*)Vs + bsel + offv);
                o[nf] = __builtin_amdgcn_mfma_f32_16x16x32_bf16(pfr, vb, o[nf], 0, 0, 0);
            }
        }
        __builtin_amdgcn_s_setprio(0);

        // ---- publish tile it+1 into the other buffer (no barrier needed) ----
        if (nit < total) {
            const int b2 = (nit & 1) << 14;
#pragma unroll
            for (int j = 0; j < 4; ++j) {
                *(u32x4*)((char*)Ks + b2 + loK + j * 16 * 256) = pk[j];
                *(u32x4*)((char*)Vs + b2 + loV + j * 32 * 128) = pv[j];
            }
        }
    }

    // ---- final epilogue for q-tile 31-px ----
    float rinv[4];
#pragma unroll
    for (int i = 0; i < 4; ++i) rinv[i] = 1.f / l_run[i];
    const size_t orow = (size_t)(b * T_SEQ + q0 + w * 16 + ((l >> 4) << 2));
#pragma unroll
    for (int nf = 0; nf < 8; ++nf) {
        const int col = h * HD + nf * 16 + (l & 15);
#pragma unroll
        for (int i = 0; i < 4; ++i)
            AO[(orow + i) * DM + col] = f2bf(o[nf][i] * rinv[i]);
    }
}

// ---------------------------------------------------------------------------
extern "C" void kernel_launch(void* const* d_in, const int* in_sizes, int n_in,
                              void* d_out, int out_size, void* d_ws, size_t ws_size,
                              hipStream_t stream)
{
    const float* x      = (const float*)d_in[0];
    // d_in[1] = attn_mask (causal, analytic)
    // d_in[2] = alibi_bias (analytic)
    const float* qkv_w  = (const float*)d_in[3];
    const float* qkv_b  = (const float*)d_in[4];
    const float* proj_w = (const float*)d_in[5];
    const float* proj_b = (const float*)d_in[6];
    float* out = (float*)d_out;

    u16* ws  = (u16*)d_ws;
    u16* xb  = ws;                                   // 4096*2048
    u16* AO  = ws;                                   // alias: x dead after gemm0
    u16* qwb = ws + 8388608;                         // 3072*2048
    u16* pwb = qwb + 6291456;                        // 2048*2048
    u16* qkv = pwb + 4194304;                        // 4096*3072
    u16* Vt  = qkv + 12582912;                       // 2*4*128*2048

    cvt_f32_bf16<<<2048, 256, 0, stream>>>(x,      xb,  8388608 / 4);
    cvt_f32_bf16<<<2048, 256, 0, stream>>>(qkv_w,  qwb, 6291456 / 4);
    cvt_f32_bf16<<<1024, 256, 0, stream>>>(proj_w, pwb, 4194304 / 4);

    gemm_bt<0><<<dim3(32, 24), 256, 0, stream>>>(xb, qwb, qkv_b, qkv, nullptr, Vt,
                                                 MROWS, QKV_N, DM);
    attn_fwd<<<dim3(16, 32), 256, 0, stream>>>(qkv, Vt, AO);
    gemm_bt<1><<<dim3(32, 16), 256, 0, stream>>>(AO, pwb, proj_b, nullptr, out, nullptr,
                                                 MROWS, DM, DM);
}

// Round 7
// 201.229 us; speedup vs baseline: 1.2729x; 1.0318x over previous
//
#include <hip/hip_runtime.h>
#include <hip/hip_bf16.h>
#include <math.h>

typedef unsigned short u16;
typedef unsigned int   u32;
typedef __attribute__((ext_vector_type(8))) short bf16x8;
typedef __attribute__((ext_vector_type(4))) float f32x4;
typedef __attribute__((ext_vector_type(4))) unsigned short u16x4;
typedef __attribute__((ext_vector_type(4))) unsigned int   u32x4;

#define T_SEQ 2048
#define BATCH 2
#define NHEAD 16
#define KVHEADS 4
#define HD 128
#define DM 2048
#define QKV_N 3072
#define MROWS 4096

__device__ __forceinline__ float bf2f(u16 u) {
    union { u32 i; float f; } v; v.i = ((u32)u) << 16; return v.f;
}
__device__ __forceinline__ u16 f2bf(float f) {
    u32 x = __float_as_uint(f);
    u32 r = (x + 0x7fffu + ((x >> 16) & 1u)) >> 16;
    return (u16)r;
}

// async global->LDS, 16B per lane; dest = wave-uniform base + lane*16
__device__ __forceinline__ void gl16(const void* g, void* lds) {
    __builtin_amdgcn_global_load_lds(
        (const __attribute__((address_space(1))) void*)g,
        (__attribute__((address_space(3))) void*)lds, 16, 0, 0);
}

// ---------------------------------------------------------------------------
__global__ void reset_u32(u32* p, u32 v) { *p = v; }

// ---------------------------------------------------------------------------
// fp32 -> bf16 elementwise convert
// ---------------------------------------------------------------------------
__global__ void cvt_f32_bf16(const float* __restrict__ in, u16* __restrict__ out, int nq)
{
    int i = blockIdx.x * blockDim.x + threadIdx.x;
    const int stride = gridDim.x * blockDim.x;
    for (; i < nq; i += stride) {
        f32x4 v = ((const f32x4*)in)[i];
        u16x4 o = { f2bf(v[0]), f2bf(v[1]), f2bf(v[2]), f2bf(v[3]) };
        ((u16x4*)out)[i] = o;
    }
}

// ---------------------------------------------------------------------------
// GEMM: C[M,N] = A[M,K] @ B[N,K]^T + bias  (bf16 tiles, fp32 acc)
// 128x128 tile, BK=64, 256 threads. Staging via global_load_lds width=16:
// linear LDS dest, pre-swizzled global source (src slot = slot^(row&7)),
// swizzled ds_read_b128 (byte ^= (row&7)<<4) -> involution consistent.
// ---------------------------------------------------------------------------
template <int EPI>
__global__ __launch_bounds__(256, 3)
void gemm_bt(const u16* __restrict__ A, const u16* __restrict__ Bw,
             const float* __restrict__ bias, u16* __restrict__ C,
             float* __restrict__ Cf, u16* __restrict__ Vt, int M, int N, int K)
{
    __shared__ __align__(16) u16 As[128 * 64];
    __shared__ __align__(16) u16 Bs[128 * 64];

    const int tid = threadIdx.x;
    const int l = tid & 63;
    const int w = tid >> 6;
    const int wr = w >> 1, wc = w & 1;
    const int bm = blockIdx.x, bn = blockIdx.y;

    const int lrow = l >> 3;
    const int lsl  = (l & 7) ^ lrow;
    const size_t aBase = (size_t)(bm * 128 + w * 8 + lrow) * K + lsl * 8;
    const size_t bBase = (size_t)(bn * 128 + w * 8 + lrow) * K + lsl * 8;

    const int sw = (l & 7) << 4;
    int offA[4], offB[4];
#pragma unroll
    for (int mf = 0; mf < 4; ++mf)
        offA[mf] = (wr * 64 + mf * 16 + (l & 15)) * 128 + (((l >> 4) * 16) ^ sw);
#pragma unroll
    for (int nf = 0; nf < 4; ++nf)
        offB[nf] = (wc * 64 + nf * 16 + (l & 15)) * 128 + (((l >> 4) * 16) ^ sw);

    f32x4 acc[4][4];
#pragma unroll
    for (int i = 0; i < 4; ++i)
#pragma unroll
        for (int j = 0; j < 4; ++j)
            acc[i][j] = (f32x4){0.f, 0.f, 0.f, 0.f};

    const int nK = K >> 6;
    for (int kt = 0; kt < nK; ++kt) {
        __syncthreads();
#pragma unroll
        for (int j = 0; j < 4; ++j) {
            gl16(A  + aBase + (size_t)j * 32 * K + kt * 64,
                 (char*)As + (w * 8 + j * 32) * 128);
            gl16(Bw + bBase + (size_t)j * 32 * K + kt * 64,
                 (char*)Bs + (w * 8 + j * 32) * 128);
        }
        __syncthreads();
#pragma unroll
        for (int kk = 0; kk < 2; ++kk) {
            bf16x8 af[4], bfr[4];
#pragma unroll
            for (int mf = 0; mf < 4; ++mf)
                af[mf] = *(const bf16x8*)((const char*)As + (offA[mf] ^ (kk << 6)));
#pragma unroll
            for (int nf = 0; nf < 4; ++nf)
                bfr[nf] = *(const bf16x8*)((const char*)Bs + (offB[nf] ^ (kk << 6)));
            __builtin_amdgcn_s_setprio(1);
#pragma unroll
            for (int mf = 0; mf < 4; ++mf)
#pragma unroll
                for (int nf = 0; nf < 4; ++nf)
                    acc[mf][nf] = __builtin_amdgcn_mfma_f32_16x16x32_bf16(
                        af[mf], bfr[nf], acc[mf][nf], 0, 0, 0);
            __builtin_amdgcn_s_setprio(0);
        }
    }

    const int row0 = bm * 128 + wr * 64 + ((l >> 4) << 2);
    const int col0 = bn * 128 + wc * 64 + (l & 15);
#pragma unroll
    for (int mf = 0; mf < 4; ++mf) {
#pragma unroll
        for (int nf = 0; nf < 4; ++nf) {
            const int row = row0 + mf * 16;
            const int col = col0 + nf * 16;
            const float bv = bias[col];
            float v0 = acc[mf][nf][0] + bv;
            float v1 = acc[mf][nf][1] + bv;
            float v2 = acc[mf][nf][2] + bv;
            float v3 = acc[mf][nf][3] + bv;
            if (EPI == 0) {
                if (col < 2560) {
                    C[(size_t)(row + 0) * QKV_N + col] = f2bf(v0);
                    C[(size_t)(row + 1) * QKV_N + col] = f2bf(v1);
                    C[(size_t)(row + 2) * QKV_N + col] = f2bf(v2);
                    C[(size_t)(row + 3) * QKV_N + col] = f2bf(v3);
                } else {
                    const int dd = col - 2560;
                    const int kv = dd >> 7;
                    const int d = dd & 127;
                    const int bidx = row >> 11;
                    const int tt = row & 2047;
                    u16x4 pv = {f2bf(v0), f2bf(v1), f2bf(v2), f2bf(v3)};
                    *(u16x4*)(Vt + ((size_t)((bidx * KVHEADS + kv) * HD + d)) * T_SEQ + tt) = pv;
                }
            } else {
                Cf[(size_t)(row + 0) * DM + col] = v0;
                Cf[(size_t)(row + 1) * DM + col] = v1;
                Cf[(size_t)(row + 2) * DM + col] = v2;
                Cf[(size_t)(row + 3) * DM + col] = v3;
            }
        }
    }
}

// ---------------------------------------------------------------------------
// Flash attention v5: work-queue + ALiBi windowing + reverse-order defer-max.
// 1024 items = (b,h,qt), ordered qt-descending (longest first). Blocks 0..511
// take item=blockIdx statically; more items popped via atomic ctr (init 512).
// Per item: iterate KV tiles jt = qt DOWN to jt_min = max(0, qt-W1) where
// W1 = floor(36/(64*slope))+2  (dropped tiles contribute < e^-36 -- exact).
// Reverse order => running max set by diagonal tile => defer-max skip path
// (no corr/rescale) taken almost always. Softmax in log2 domain (exp2).
// Structure per tile = r6's dbuf: one barrier, reg-prefetch, publish late.
// ---------------------------------------------------------------------------
__global__ __launch_bounds__(256, 2)
void attn_fwd(const u16* __restrict__ qkv, const u16* __restrict__ Vt,
              u16* __restrict__ AO, u32* __restrict__ ctr)
{
    __shared__ __align__(16) u16 Ks[2 * 64 * 128];   // 2 x 16KB
    __shared__ __align__(16) u16 Vs[2 * 64 * 128];   // 2 x 16KB
    __shared__ __align__(16) u16 Ps[4 * 16 * 64];    // per-wave P, 8KB
    __shared__ int sh_item;

    const int tid = threadIdx.x;
    const int l = tid & 63;
    const int w = tid >> 6;

    const int sw = (l & 7) << 4;
    int offK0[4];
#pragma unroll
    for (int nf = 0; nf < 4; ++nf)
        offK0[nf] = (nf * 16 + (l & 15)) * 256 + (((l >> 4) * 16) ^ sw);

    const int rk = tid >> 4, skk = tid & 15;
    const int loK = rk * 256 + ((skk * 16) ^ ((rk & 7) << 4));
    const int rv = tid >> 3, svv = tid & 7;
    const int loV = rv * 128 + ((svv * 16) ^ ((rv & 7) << 4));

    const float LOG2E = 1.4426950408889634f;
    const float scale2 = 0.08838834764831845f * LOG2E;  // (1/sqrt(128))*log2e

    int item = blockIdx.x;   // static first item (longest-first ordering)

    for (;;) {
        __syncthreads();     // prior item's LDS reads complete
        if (item < 0 && tid == 0) sh_item = (int)atomicAdd(ctr, 1u);
        __syncthreads();
        if (item < 0) item = sh_item;
        if (item >= 1024) break;

        const int qt = 31 - (item >> 5);
        const int bh = item & 31;
        const int b = bh >> 4;
        const int h = bh & 15;
        const int kvh = h >> 2;
        const int q0 = qt << 6;

        const float slope  = exp2f(-0.5f * (float)(h + 1));
        const float slope2 = slope * LOG2E;
        const int W1 = (int)(36.0f * exp2f(0.5f * (float)(h + 1)) * (1.0f / 64.0f)) + 2;
        const int jt_min = (qt - W1 > 0) ? (qt - W1) : 0;

        const size_t gK0 = (size_t)(b * T_SEQ + rk) * QKV_N + 2048 + kvh * HD + skk * 8;
        const size_t gV0 = (size_t)((b * KVHEADS + kvh) * HD + rv) * T_SEQ + svv * 8;

        // Q fragments in registers
        const size_t qrow_off = (size_t)h * HD + ((l >> 4) << 3);
        bf16x8 qreg[4];
#pragma unroll
        for (int kk = 0; kk < 4; ++kk)
            qreg[kk] = *(const bf16x8*)(qkv +
                (size_t)(b * T_SEQ + q0 + w * 16 + (l & 15)) * QKV_N + qrow_off + kk * 32);

        float m_run[4], l_run[4];
        f32x4 o[8];
#pragma unroll
        for (int i = 0; i < 4; ++i) { m_run[i] = -__builtin_inff(); l_run[i] = 0.f; }
#pragma unroll
        for (int nf = 0; nf < 8; ++nf) o[nf] = (f32x4){0.f, 0.f, 0.f, 0.f};

        // prologue: tile jt=qt into regs, publish to buffer 0
        u32x4 pk[4], pv[4];
#pragma unroll
        for (int j = 0; j < 4; ++j) {
            pk[j] = *(const u32x4*)(qkv + gK0 + (size_t)(q0 + j * 16) * QKV_N);
            pv[j] = *(const u32x4*)(Vt + gV0 + q0 + (size_t)j * 32 * T_SEQ);
        }
#pragma unroll
        for (int j = 0; j < 4; ++j) {
            *(u32x4*)((char*)Ks + loK + j * 16 * 256) = pk[j];
            *(u32x4*)((char*)Vs + loV + j * 32 * 128) = pv[j];
        }

        const int tb = q0 + w * 16 + ((l >> 4) << 2);

        for (int c = 0, jt = qt; jt >= jt_min; --jt, ++c) {
            const int s0 = jt << 6;
            const int bsel = (c & 1) << 14;

            __syncthreads();   // buf[c&1] staged; frees buf[(c+1)&1]

            if (jt > jt_min) {
                const int ns0 = (jt - 1) << 6;
#pragma unroll
                for (int j = 0; j < 4; ++j) {
                    pk[j] = *(const u32x4*)(qkv + gK0 + (size_t)(ns0 + j * 16) * QKV_N);
                    pv[j] = *(const u32x4*)(Vt + gV0 + ns0 + (size_t)j * 32 * T_SEQ);
                }
            }

            // ---- S = Q K^T ----
            f32x4 sc[4];
#pragma unroll
            for (int nf = 0; nf < 4; ++nf) sc[nf] = (f32x4){0.f, 0.f, 0.f, 0.f};
            __builtin_amdgcn_s_setprio(1);
#pragma unroll
            for (int kk = 0; kk < 4; ++kk) {
#pragma unroll
                for (int nf = 0; nf < 4; ++nf) {
                    bf16x8 kb = *(const bf16x8*)((const char*)Ks + bsel + (offK0[nf] ^ (kk << 6)));
                    sc[nf] = __builtin_amdgcn_mfma_f32_16x16x32_bf16(qreg[kk], kb, sc[nf], 0, 0, 0);
                }
            }
            __builtin_amdgcn_s_setprio(0);

            // ---- scale + alibi (log2 domain) + diag mask (c==0 only) ----
            float vals[4][4];
#pragma unroll
            for (int nf = 0; nf < 4; ++nf) {
                const int scol = s0 + nf * 16 + (l & 15);
#pragma unroll
                for (int i = 0; i < 4; ++i) {
                    const int trow = tb + i;
                    const float xv = sc[nf][i] * scale2 + slope2 * (float)(scol - trow);
                    vals[nf][i] = (c == 0 && scol > trow) ? -__builtin_inff() : xv;
                }
            }

            // ---- online softmax, defer-max fast path ----
            float tm[4];
#pragma unroll
            for (int i = 0; i < 4; ++i) {
                float mx = fmaxf(fmaxf(vals[0][i], vals[1][i]), fmaxf(vals[2][i], vals[3][i]));
#pragma unroll
                for (int d = 1; d < 16; d <<= 1) mx = fmaxf(mx, __shfl_xor(mx, d, 64));
                tm[i] = mx;
            }
            const bool nskip = (tm[0] <= m_run[0] + 11.f) && (tm[1] <= m_run[1] + 11.f) &&
                               (tm[2] <= m_run[2] + 11.f) && (tm[3] <= m_run[3] + 11.f);
            float ps[4] = {0.f, 0.f, 0.f, 0.f};
            if (__all(nskip)) {
                // keep old max; P bounded by 2^11, no rescale needed
#pragma unroll
                for (int nf = 0; nf < 4; ++nf)
#pragma unroll
                    for (int i = 0; i < 4; ++i) {
                        const float p = exp2f(vals[nf][i] - m_run[i]);
                        vals[nf][i] = p;
                        ps[i] += p;
                    }
#pragma unroll
                for (int i = 0; i < 4; ++i) {
#pragma unroll
                    for (int d = 1; d < 16; d <<= 1) ps[i] += __shfl_xor(ps[i], d, 64);
                    l_run[i] += ps[i];
                }
            } else {
                float corr[4];
#pragma unroll
                for (int i = 0; i < 4; ++i) {
                    const float mn = fmaxf(m_run[i], tm[i]);
                    corr[i] = exp2f(m_run[i] - mn);
                    m_run[i] = mn;
                }
#pragma unroll
                for (int nf = 0; nf < 4; ++nf)
#pragma unroll
                    for (int i = 0; i < 4; ++i) {
                        const float p = exp2f(vals[nf][i] - m_run[i]);
                        vals[nf][i] = p;
                        ps[i] += p;
                    }
#pragma unroll
                for (int i = 0; i < 4; ++i) {
#pragma unroll
                    for (int d = 1; d < 16; d <<= 1) ps[i] += __shfl_xor(ps[i], d, 64);
                    l_run[i] = l_run[i] * corr[i] + ps[i];
                }
#pragma unroll
                for (int nf = 0; nf < 8; ++nf) {
                    o[nf][0] *= corr[0]; o[nf][1] *= corr[1];
                    o[nf][2] *= corr[2]; o[nf][3] *= corr[3];
                }
            }

            // ---- P -> per-wave LDS (bf16, swizzled) ----
            const int pbase = w * 2048;
#pragma unroll
            for (int nf = 0; nf < 4; ++nf)
#pragma unroll
                for (int i = 0; i < 4; ++i) {
                    const int r = ((l >> 4) << 2) + i;
                    const int off = pbase + ((r * 128 + nf * 32 + ((l & 15) << 1)) ^ ((r & 7) << 4));
                    *(u16*)((char*)Ps + off) = f2bf(vals[nf][i]);
                }

            // ---- O += P @ V ----
            const int rp = l & 15;
            __builtin_amdgcn_s_setprio(1);
#pragma unroll
            for (int kk = 0; kk < 2; ++kk) {
                bf16x8 pfr = *(const bf16x8*)((const char*)Ps + pbase +
                              (rp * 128 + ((((l >> 4) * 16) ^ sw) ^ (kk << 6))));
#pragma unroll
                for (int nf = 0; nf < 8; ++nf) {
                    const int offv = (nf * 16 + (l & 15)) * 128 + ((((l >> 4) * 16) ^ sw) ^ (kk << 6));
                    bf16x8 vb = *(const bf16x8*)((const char*)Vs + bsel + offv);
                    o[nf] = __builtin_amdgcn_mfma_f32_16x16x32_bf16(pfr, vb, o[nf], 0, 0, 0);
                }
            }
            __builtin_amdgcn_s_setprio(0);

            // ---- publish tile jt-1 into the other buffer ----
            if (jt > jt_min) {
                const int b2 = ((c + 1) & 1) << 14;
#pragma unroll
                for (int j = 0; j < 4; ++j) {
                    *(u32x4*)((char*)Ks + b2 + loK + j * 16 * 256) = pk[j];
                    *(u32x4*)((char*)Vs + b2 + loV + j * 32 * 128) = pv[j];
                }
            }
        }

        // ---- epilogue ----
        float rinv[4];
#pragma unroll
        for (int i = 0; i < 4; ++i) rinv[i] = 1.f / l_run[i];
        const size_t orow = (size_t)(b * T_SEQ + q0 + w * 16 + ((l >> 4) << 2));
#pragma unroll
        for (int nf = 0; nf < 8; ++nf) {
            const int col = h * HD + nf * 16 + (l & 15);
#pragma unroll
            for (int i = 0; i < 4; ++i)
                AO[(orow + i) * DM + col] = f2bf(o[nf][i] * rinv[i]);
        }

        item = -1;   // pop next from queue
    }
}

// ---------------------------------------------------------------------------
extern "C" void kernel_launch(void* const* d_in, const int* in_sizes, int n_in,
                              void* d_out, int out_size, void* d_ws, size_t ws_size,
                              hipStream_t stream)
{
    const float* x      = (const float*)d_in[0];
    // d_in[1] = attn_mask (causal, analytic)
    // d_in[2] = alibi_bias (analytic)
    const float* qkv_w  = (const float*)d_in[3];
    const float* qkv_b  = (const float*)d_in[4];
    const float* proj_w = (const float*)d_in[5];
    const float* proj_b = (const float*)d_in[6];
    float* out = (float*)d_out;

    u16* ws  = (u16*)d_ws;
    u16* xb  = ws;                                   // 4096*2048
    u16* AO  = ws;                                   // alias: x dead after gemm0
    u16* qwb = ws + 8388608;                         // 3072*2048
    u16* pwb = qwb + 6291456;                        // 2048*2048
    u16* qkv = pwb + 4194304;                        // 4096*3072
    u16* Vt  = qkv + 12582912;                       // 2*4*128*2048
    u32* ctr = (u32*)(ws + 33554432);                // work-queue counter

    reset_u32<<<1, 1, 0, stream>>>(ctr, 512u);       // first 512 items static
    cvt_f32_bf16<<<2048, 256, 0, stream>>>(x,      xb,  8388608 / 4);
    cvt_f32_bf16<<<2048, 256, 0, stream>>>(qkv_w,  qwb, 6291456 / 4);
    cvt_f32_bf16<<<1024, 256, 0, stream>>>(proj_w, pwb, 4194304 / 4);

    gemm_bt<0><<<dim3(32, 24), 256, 0, stream>>>(xb, qwb, qkv_b, qkv, nullptr, Vt,
                                                 MROWS, QKV_N, DM);
    attn_fwd<<<dim3(512), 256, 0, stream>>>(qkv, Vt, AO, ctr);
    gemm_bt<1><<<dim3(32, 16), 256, 0, stream>>>(AO, pwb, proj_b, nullptr, out, nullptr,
                                                 MROWS, DM, DM);
}

// Round 8
// 187.572 us; speedup vs baseline: 1.3656x; 1.0728x over previous
//
#include <hip/hip_runtime.h>
#include <hip/hip_bf16.h>
#include <math.h>

typedef unsigned short u16;
typedef unsigned int   u32;
typedef __attribute__((ext_vector_type(8))) short bf16x8;
typedef __attribute__((ext_vector_type(4))) float f32x4;
typedef __attribute__((ext_vector_type(4))) unsigned short u16x4;
typedef __attribute__((ext_vector_type(4))) unsigned int   u32x4;

#define T_SEQ 2048
#define BATCH 2
#define NHEAD 16
#define KVHEADS 4
#define HD 128
#define DM 2048
#define QKV_N 3072
#define MROWS 4096

__device__ __forceinline__ float bf2f(u16 u) {
    union { u32 i; float f; } v; v.i = ((u32)u) << 16; return v.f;
}
__device__ __forceinline__ u16 f2bf(float f) {
    u32 x = __float_as_uint(f);
    u32 r = (x + 0x7fffu + ((x >> 16) & 1u)) >> 16;
    return (u16)r;
}

// async global->LDS, 16B per lane; dest = wave-uniform base + lane*16
__device__ __forceinline__ void gl16(const void* g, void* lds) {
    __builtin_amdgcn_global_load_lds(
        (const __attribute__((address_space(1))) void*)g,
        (__attribute__((address_space(3))) void*)lds, 16, 0, 0);
}

__device__ __forceinline__ int alibi_w1(int h) {
    // W1 = floor(36 * 2^((h+1)/2) / 64) + 2 ; beyond this many 64-tiles the
    // ALiBi bias alone makes contributions < e^-36 relative (exact drop).
    return (int)(36.0f * exp2f(0.5f * (float)(h + 1)) * (1.0f / 64.0f)) + 2;
}

// ---------------------------------------------------------------------------
__global__ void reset_u32(u32* p, u32 v) { *p = v; }

// ---------------------------------------------------------------------------
__global__ void cvt_f32_bf16(const float* __restrict__ in, u16* __restrict__ out, int nq)
{
    int i = blockIdx.x * blockDim.x + threadIdx.x;
    const int stride = gridDim.x * blockDim.x;
    for (; i < nq; i += stride) {
        f32x4 v = ((const f32x4*)in)[i];
        u16x4 o = { f2bf(v[0]), f2bf(v[1]), f2bf(v[2]), f2bf(v[3]) };
        ((u16x4*)out)[i] = o;
    }
}

// ---------------------------------------------------------------------------
// GEMM (unchanged from r7): 128x128 tile, BK=64, global_load_lds staging.
// ---------------------------------------------------------------------------
template <int EPI>
__global__ __launch_bounds__(256, 3)
void gemm_bt(const u16* __restrict__ A, const u16* __restrict__ Bw,
             const float* __restrict__ bias, u16* __restrict__ C,
             float* __restrict__ Cf, u16* __restrict__ Vt, int M, int N, int K)
{
    __shared__ __align__(16) u16 As[128 * 64];
    __shared__ __align__(16) u16 Bs[128 * 64];

    const int tid = threadIdx.x;
    const int l = tid & 63;
    const int w = tid >> 6;
    const int wr = w >> 1, wc = w & 1;
    const int bm = blockIdx.x, bn = blockIdx.y;

    const int lrow = l >> 3;
    const int lsl  = (l & 7) ^ lrow;
    const size_t aBase = (size_t)(bm * 128 + w * 8 + lrow) * K + lsl * 8;
    const size_t bBase = (size_t)(bn * 128 + w * 8 + lrow) * K + lsl * 8;

    const int sw = (l & 7) << 4;
    int offA[4], offB[4];
#pragma unroll
    for (int mf = 0; mf < 4; ++mf)
        offA[mf] = (wr * 64 + mf * 16 + (l & 15)) * 128 + (((l >> 4) * 16) ^ sw);
#pragma unroll
    for (int nf = 0; nf < 4; ++nf)
        offB[nf] = (wc * 64 + nf * 16 + (l & 15)) * 128 + (((l >> 4) * 16) ^ sw);

    f32x4 acc[4][4];
#pragma unroll
    for (int i = 0; i < 4; ++i)
#pragma unroll
        for (int j = 0; j < 4; ++j)
            acc[i][j] = (f32x4){0.f, 0.f, 0.f, 0.f};

    const int nK = K >> 6;
    for (int kt = 0; kt < nK; ++kt) {
        __syncthreads();
#pragma unroll
        for (int j = 0; j < 4; ++j) {
            gl16(A  + aBase + (size_t)j * 32 * K + kt * 64,
                 (char*)As + (w * 8 + j * 32) * 128);
            gl16(Bw + bBase + (size_t)j * 32 * K + kt * 64,
                 (char*)Bs + (w * 8 + j * 32) * 128);
        }
        __syncthreads();
#pragma unroll
        for (int kk = 0; kk < 2; ++kk) {
            bf16x8 af[4], bfr[4];
#pragma unroll
            for (int mf = 0; mf < 4; ++mf)
                af[mf] = *(const bf16x8*)((const char*)As + (offA[mf] ^ (kk << 6)));
#pragma unroll
            for (int nf = 0; nf < 4; ++nf)
                bfr[nf] = *(const bf16x8*)((const char*)Bs + (offB[nf] ^ (kk << 6)));
            __builtin_amdgcn_s_setprio(1);
#pragma unroll
            for (int mf = 0; mf < 4; ++mf)
#pragma unroll
                for (int nf = 0; nf < 4; ++nf)
                    acc[mf][nf] = __builtin_amdgcn_mfma_f32_16x16x32_bf16(
                        af[mf], bfr[nf], acc[mf][nf], 0, 0, 0);
            __builtin_amdgcn_s_setprio(0);
        }
    }

    const int row0 = bm * 128 + wr * 64 + ((l >> 4) << 2);
    const int col0 = bn * 128 + wc * 64 + (l & 15);
#pragma unroll
    for (int mf = 0; mf < 4; ++mf) {
#pragma unroll
        for (int nf = 0; nf < 4; ++nf) {
            const int row = row0 + mf * 16;
            const int col = col0 + nf * 16;
            const float bv = bias[col];
            float v0 = acc[mf][nf][0] + bv;
            float v1 = acc[mf][nf][1] + bv;
            float v2 = acc[mf][nf][2] + bv;
            float v3 = acc[mf][nf][3] + bv;
            if (EPI == 0) {
                if (col < 2560) {
                    C[(size_t)(row + 0) * QKV_N + col] = f2bf(v0);
                    C[(size_t)(row + 1) * QKV_N + col] = f2bf(v1);
                    C[(size_t)(row + 2) * QKV_N + col] = f2bf(v2);
                    C[(size_t)(row + 3) * QKV_N + col] = f2bf(v3);
                } else {
                    const int dd = col - 2560;
                    const int kv = dd >> 7;
                    const int d = dd & 127;
                    const int bidx = row >> 11;
                    const int tt = row & 2047;
                    u16x4 pv = {f2bf(v0), f2bf(v1), f2bf(v2), f2bf(v3)};
                    *(u16x4*)(Vt + ((size_t)((bidx * KVHEADS + kv) * HD + d)) * T_SEQ + tt) = pv;
                }
            } else {
                Cf[(size_t)(row + 0) * DM + col] = v0;
                Cf[(size_t)(row + 1) * DM + col] = v1;
                Cf[(size_t)(row + 2) * DM + col] = v2;
                Cf[(size_t)(row + 3) * DM + col] = v3;
            }
        }
    }
}

// ---------------------------------------------------------------------------
// Flash attention v6: split-K segments + work queue + ALiBi window +
// shuffle-free defer-max + l-via-ones-MFMA.
// Item space (1536): [0,512)    seg0 of qt 31..16  (static, blockIdx)
//                    [512,1024) seg1 of qt 31..16  (exists iff split)
//                    [1024,1536) seg0 of qt 15..0
// split = (qt>=16 && W1>=16): seg0 = 16 tiles at the diagonal, seg1 = rest.
// Split segments write fp32 partials (O,m,l) to PWS; attn_combine merges.
// PWS stride per seg = 8448 floats: [64][128] O + [64] m + [64] l.
// ---------------------------------------------------------------------------
#define PWS_SEG 8448
__global__ __launch_bounds__(256, 2)
void attn_fwd(const u16* __restrict__ qkv, const u16* __restrict__ Vt,
              u16* __restrict__ AO, u32* __restrict__ ctr,
              float* __restrict__ PWS)
{
    __shared__ __align__(16) u16 Ks[2 * 64 * 128];   // 2 x 16KB
    __shared__ __align__(16) u16 Vs[2 * 64 * 128];   // 2 x 16KB
    __shared__ __align__(16) u16 Ps[4 * 16 * 64];    // per-wave P, 8KB
    __shared__ int sh_item;

    const int tid = threadIdx.x;
    const int l = tid & 63;
    const int w = tid >> 6;

    const int sw = (l & 7) << 4;
    int offK0[4];
#pragma unroll
    for (int nf = 0; nf < 4; ++nf)
        offK0[nf] = (nf * 16 + (l & 15)) * 256 + (((l >> 4) * 16) ^ sw);

    const int rk = tid >> 4, skk = tid & 15;
    const int loK = rk * 256 + ((skk * 16) ^ ((rk & 7) << 4));
    const int rv = tid >> 3, svv = tid & 7;
    const int loV = rv * 128 + ((svv * 16) ^ ((rv & 7) << 4));

    const float LOG2E = 1.4426950408889634f;
    const float scale2 = 0.08838834764831845f * LOG2E;
    const bf16x8 ones = {(short)0x3F80, (short)0x3F80, (short)0x3F80, (short)0x3F80,
                         (short)0x3F80, (short)0x3F80, (short)0x3F80, (short)0x3F80};

    int item = blockIdx.x;   // static first item

    for (;;) {
        __syncthreads();     // prior item's LDS reads done; sh_item reusable
        if (item < 0 && tid == 0) sh_item = (int)atomicAdd(ctr, 1u);
        __syncthreads();
        if (item < 0) item = sh_item;
        if (item >= 1536) break;

        int seg, qt, bh;
        if (item < 512)       { seg = 0; qt = 31 - (item >> 5);          bh = item & 31; }
        else if (item < 1024) { seg = 1; qt = 31 - ((item - 512) >> 5);  bh = item & 31; }
        else                  { seg = 0; qt = 15 - ((item - 1024) >> 5); bh = item & 31; }
        const int b = bh >> 4;
        const int h = bh & 15;
        const int kvh = h >> 2;
        const int q0 = qt << 6;

        const float slope2 = exp2f(-0.5f * (float)(h + 1)) * LOG2E;
        const int W1 = alibi_w1(h);
        const int jt_min = (qt - W1 > 0) ? (qt - W1) : 0;
        const bool split = (qt >= 16) && (W1 >= 16);
        if (seg == 1 && !split) { item = -1; continue; }

        const int jt_hi = seg ? (qt - 16) : qt;
        const int jt_lo = seg ? jt_min : (split ? (qt - 15) : jt_min);

        const size_t gK0 = (size_t)(b * T_SEQ + rk) * QKV_N + 2048 + kvh * HD + skk * 8;
        const size_t gV0 = (size_t)((b * KVHEADS + kvh) * HD + rv) * T_SEQ + svv * 8;

        // Q fragments in registers
        const size_t qrow_off = (size_t)h * HD + ((l >> 4) << 3);
        bf16x8 qreg[4];
#pragma unroll
        for (int kk = 0; kk < 4; ++kk)
            qreg[kk] = *(const bf16x8*)(qkv +
                (size_t)(b * T_SEQ + q0 + w * 16 + (l & 15)) * QKV_N + qrow_off + kk * 32);

        float m_run[4];
        f32x4 o[8];
        f32x4 lacc = (f32x4){0.f, 0.f, 0.f, 0.f};
#pragma unroll
        for (int i = 0; i < 4; ++i) m_run[i] = -1e30f;
#pragma unroll
        for (int nf = 0; nf < 8; ++nf) o[nf] = (f32x4){0.f, 0.f, 0.f, 0.f};

        // alibi base: abase[nf][i] = slope2*(scol - trow) at jt = jt_hi
        const int tb = q0 + w * 16 + ((l >> 4) << 2);
        const float dslope = slope2 * 64.0f;
        float abase[4][4];
#pragma unroll
        for (int nf = 0; nf < 4; ++nf)
#pragma unroll
            for (int i = 0; i < 4; ++i)
                abase[nf][i] = slope2 * (float)((jt_hi << 6) + nf * 16 + (l & 15) - (tb + i));

        // prologue: tile jt_hi into regs, publish to buffer 0
        u32x4 pk[4], pv[4];
#pragma unroll
        for (int j = 0; j < 4; ++j) {
            pk[j] = *(const u32x4*)(qkv + gK0 + (size_t)((jt_hi << 6) + j * 16) * QKV_N);
            pv[j] = *(const u32x4*)(Vt + gV0 + (jt_hi << 6) + (size_t)j * 32 * T_SEQ);
        }
#pragma unroll
        for (int j = 0; j < 4; ++j) {
            *(u32x4*)((char*)Ks + loK + j * 16 * 256) = pk[j];
            *(u32x4*)((char*)Vs + loV + j * 32 * 128) = pv[j];
        }

        for (int c = 0, jt = jt_hi; jt >= jt_lo; --jt, ++c) {
            const int bsel = (c & 1) << 14;

            __syncthreads();   // buf[c&1] staged; frees buf[(c+1)&1]

            if (jt > jt_lo) {
                const int ns0 = (jt - 1) << 6;
#pragma unroll
                for (int j = 0; j < 4; ++j) {
                    pk[j] = *(const u32x4*)(qkv + gK0 + (size_t)(ns0 + j * 16) * QKV_N);
                    pv[j] = *(const u32x4*)(Vt + gV0 + ns0 + (size_t)j * 32 * T_SEQ);
                }
            }

            // ---- S = Q K^T ----
            f32x4 sc[4];
#pragma unroll
            for (int nf = 0; nf < 4; ++nf) sc[nf] = (f32x4){0.f, 0.f, 0.f, 0.f};
            __builtin_amdgcn_s_setprio(1);
#pragma unroll
            for (int kk = 0; kk < 4; ++kk) {
#pragma unroll
                for (int nf = 0; nf < 4; ++nf) {
                    bf16x8 kb = *(const bf16x8*)((const char*)Ks + bsel + (offK0[nf] ^ (kk << 6)));
                    sc[nf] = __builtin_amdgcn_mfma_f32_16x16x32_bf16(qreg[kk], kb, sc[nf], 0, 0, 0);
                }
            }
            __builtin_amdgcn_s_setprio(0);

            // ---- vals = sc*scale2 + abase (log2 domain) ----
            float vals[4][4];
#pragma unroll
            for (int nf = 0; nf < 4; ++nf)
#pragma unroll
                for (int i = 0; i < 4; ++i) {
                    vals[nf][i] = fmaf(sc[nf][i], scale2, abase[nf][i]);
                    abase[nf][i] -= dslope;
                }
            if (seg == 0 && c == 0) {   // diagonal tile: causal mask
                const int s0 = jt << 6;
#pragma unroll
                for (int nf = 0; nf < 4; ++nf) {
                    const int scol = s0 + nf * 16 + (l & 15);
#pragma unroll
                    for (int i = 0; i < 4; ++i)
                        if (scol > tb + i) vals[nf][i] = -__builtin_inff();
                }
            }

            // ---- shuffle-free defer-max check ----
            float lm[4];
#pragma unroll
            for (int i = 0; i < 4; ++i)
                lm[i] = fmaxf(fmaxf(vals[0][i], vals[1][i]), fmaxf(vals[2][i], vals[3][i]));
            const bool ok = (lm[0] <= m_run[0] + 10.f) && (lm[1] <= m_run[1] + 10.f) &&
                            (lm[2] <= m_run[2] + 10.f) && (lm[3] <= m_run[3] + 10.f);
            if (!__all(ok)) {
                float corr[4];
#pragma unroll
                for (int i = 0; i < 4; ++i) {
                    float mx = lm[i];
#pragma unroll
                    for (int d = 1; d < 16; d <<= 1) mx = fmaxf(mx, __shfl_xor(mx, d, 64));
                    const float mn = fmaxf(m_run[i], mx);
                    corr[i] = exp2f(m_run[i] - mn);
                    m_run[i] = mn;
                }
#pragma unroll
                for (int nf = 0; nf < 8; ++nf) {
                    o[nf][0] *= corr[0]; o[nf][1] *= corr[1];
                    o[nf][2] *= corr[2]; o[nf][3] *= corr[3];
                }
                lacc[0] *= corr[0]; lacc[1] *= corr[1];
                lacc[2] *= corr[2]; lacc[3] *= corr[3];
            }

            // ---- P = exp2(vals - m) -> per-wave LDS (bf16, swizzled) ----
            const int pbase = w * 2048;
#pragma unroll
            for (int nf = 0; nf < 4; ++nf)
#pragma unroll
                for (int i = 0; i < 4; ++i) {
                    const float p = exp2f(vals[nf][i] - m_run[i]);
                    const int r = ((l >> 4) << 2) + i;
                    const int off = pbase + ((r * 128 + nf * 32 + ((l & 15) << 1)) ^ ((r & 7) << 4));
                    *(u16*)((char*)Ps + off) = f2bf(p);
                }

            // ---- O += P @ V ; lacc += P @ ones (row-sums) ----
            const int rp = l & 15;
            __builtin_amdgcn_s_setprio(1);
#pragma unroll
            for (int kk = 0; kk < 2; ++kk) {
                bf16x8 pfr = *(const bf16x8*)((const char*)Ps + pbase +
                              (rp * 128 + ((((l >> 4) * 16) ^ sw) ^ (kk << 6))));
                lacc = __builtin_amdgcn_mfma_f32_16x16x32_bf16(pfr, ones, lacc, 0, 0, 0);
#pragma unroll
                for (int nf = 0; nf < 8; ++nf) {
                    const int offv = (nf * 16 + (l & 15)) * 128 + ((((l >> 4) * 16) ^ sw) ^ (kk << 6));
                    bf16x8 vb = *(const bf16x8*)((const char*)Vs + bsel + offv);
                    o[nf] = __builtin_amdgcn_mfma_f32_16x16x32_bf16(pfr, vb, o[nf], 0, 0, 0);
                }
            }
            __builtin_amdgcn_s_setprio(0);

            // ---- publish tile jt-1 into the other buffer ----
            if (jt > jt_lo) {
                const int b2 = ((c + 1) & 1) << 14;
#pragma unroll
                for (int j = 0; j < 4; ++j) {
                    *(u32x4*)((char*)Ks + b2 + loK + j * 16 * 256) = pk[j];
                    *(u32x4*)((char*)Vs + b2 + loV + j * 32 * 128) = pv[j];
                }
            }
        }

        // ---- epilogue ----
        if (!split) {
            float rinv[4];
#pragma unroll
            for (int i = 0; i < 4; ++i) rinv[i] = 1.f / lacc[i];
            const size_t orow = (size_t)(b * T_SEQ + q0 + w * 16 + ((l >> 4) << 2));
#pragma unroll
            for (int nf = 0; nf < 8; ++nf) {
                const int col = h * HD + nf * 16 + (l & 15);
#pragma unroll
                for (int i = 0; i < 4; ++i)
                    AO[(orow + i) * DM + col] = f2bf(o[nf][i] * rinv[i]);
            }
        } else {
            const int rid = (bh << 5) | qt;
            float* base = PWS + (size_t)(rid * 2 + seg) * PWS_SEG;
            const int row0 = w * 16 + ((l >> 4) << 2);
#pragma unroll
            for (int nf = 0; nf < 8; ++nf) {
                const int col = nf * 16 + (l & 15);
#pragma unroll
                for (int i = 0; i < 4; ++i)
                    base[(row0 + i) * 128 + col] = o[nf][i];
            }
            if ((l & 15) == 0) {
#pragma unroll
                for (int i = 0; i < 4; ++i) {
                    base[8192 + row0 + i] = m_run[i];
                    base[8256 + row0 + i] = lacc[i];
                }
            }
        }

        item = -1;   // pop next from queue
    }
}

// ---------------------------------------------------------------------------
// Combine split items: AO[row] = (O0*w0 + O1*w1) / (l0*w0 + l1*w1)
// ---------------------------------------------------------------------------
__global__ __launch_bounds__(256)
void attn_combine(const float* __restrict__ PWS, u16* __restrict__ AO)
{
    const int rid = blockIdx.x;          // (bh<<5)|qt
    const int qt = rid & 31;
    const int bh = rid >> 5;
    const int b = bh >> 4;
    const int h = bh & 15;
    if (!(qt >= 16 && alibi_w1(h) >= 16)) return;

    const float* p0 = PWS + (size_t)(rid * 2 + 0) * PWS_SEG;
    const float* p1 = PWS + (size_t)(rid * 2 + 1) * PWS_SEG;

    const int t = threadIdx.x;
    const int row = t >> 2;
    const int c0 = (t & 3) * 32;

    const float m0 = p0[8192 + row], m1 = p1[8192 + row];
    const float l0 = p0[8256 + row], l1 = p1[8256 + row];
    const float m = fmaxf(m0, m1);
    const float w0 = exp2f(m0 - m), w1 = exp2f(m1 - m);
    const float rinv = 1.f / (l0 * w0 + l1 * w1);

    const size_t ao = (size_t)(b * T_SEQ + (qt << 6) + row) * DM + h * HD + c0;
#pragma unroll
    for (int j = 0; j < 32; ++j) {
        const float v = (p0[row * 128 + c0 + j] * w0 + p1[row * 128 + c0 + j] * w1) * rinv;
        AO[ao + j] = f2bf(v);
    }
}

// ---------------------------------------------------------------------------
extern "C" void kernel_launch(void* const* d_in, const int* in_sizes, int n_in,
                              void* d_out, int out_size, void* d_ws, size_t ws_size,
                              hipStream_t stream)
{
    const float* x      = (const float*)d_in[0];
    // d_in[1] = attn_mask (causal, analytic)
    // d_in[2] = alibi_bias (analytic)
    const float* qkv_w  = (const float*)d_in[3];
    const float* qkv_b  = (const float*)d_in[4];
    const float* proj_w = (const float*)d_in[5];
    const float* proj_b = (const float*)d_in[6];
    float* out = (float*)d_out;

    u16* ws  = (u16*)d_ws;
    u16* xb  = ws;                                   // 4096*2048
    u16* AO  = ws;                                   // alias: x dead after gemm0
    u16* qwb = ws + 8388608;                         // 3072*2048
    u16* pwb = qwb + 6291456;                        // 2048*2048
    u16* qkv = pwb + 4194304;                        // 4096*3072
    u16* Vt  = qkv + 12582912;                       // 2*4*128*2048
    u32* ctr = (u32*)(ws + 33554432);                // queue counter (4B)
    float* PWS = (float*)((char*)d_ws + 67108880);   // split partials, ~69MB

    reset_u32<<<1, 1, 0, stream>>>(ctr, 512u);
    cvt_f32_bf16<<<2048, 256, 0, stream>>>(x,      xb,  8388608 / 4);
    cvt_f32_bf16<<<2048, 256, 0, stream>>>(qkv_w,  qwb, 6291456 / 4);
    cvt_f32_bf16<<<1024, 256, 0, stream>>>(proj_w, pwb, 4194304 / 4);

    gemm_bt<0><<<dim3(32, 24), 256, 0, stream>>>(xb, qwb, qkv_b, qkv, nullptr, Vt,
                                                 MROWS, QKV_N, DM);
    attn_fwd<<<dim3(512), 256, 0, stream>>>(qkv, Vt, AO, ctr, PWS);
    attn_combine<<<dim3(1024), 256, 0, stream>>>(PWS, AO);
    gemm_bt<1><<<dim3(32, 16), 256, 0, stream>>>(AO, pwb, proj_b, nullptr, out, nullptr,
                                                 MROWS, DM, DM);
}